// Round 1
// baseline (3412.956 us; speedup 1.0000x reference)
//
#include <hip/hip_runtime.h>
#include <hip/hip_bf16.h>

// GAT 2-layer forward. N=50000, E=800000 (+N self loops), IN=256,
// layer1: 8 heads x 32 (concat -> 256), relu, layer2: 256 -> 64, 1 head.
// All fp32. Softmax computed without max-subtraction (values bounded small).

#define HEADS 8
#define HID 32
#define F1 256   // IN and layer-1 output width (8*32)
#define F2 64    // layer-2 output width
#define NEG_SLOPE 0.2f

// ---------------- GEMM: C[M,N] = op(A[M,K]) @ B[K,N] ----------------
// BM=64, BN=64, BK=16, 256 threads, 4x4 micro-tile. K, N multiples of 16/64.
template<bool RELU_IN>
__global__ void gemm_kernel(const float* __restrict__ A,
                            const float* __restrict__ B,
                            float* __restrict__ C,
                            int M, int N, int K) {
    __shared__ float As[16][65];  // [k][m]
    __shared__ float Bs[16][65];  // [k][n]
    const int tid = threadIdx.x;
    const int tx = tid & 15;         // 0..15  (cols)
    const int ty = tid >> 4;         // 0..15  (rows)
    const int brow = blockIdx.x * 64;
    const int bcol = blockIdx.y * 64;

    float acc[4][4] = {};

    for (int k0 = 0; k0 < K; k0 += 16) {
        // Load A tile: 64 rows x 16 k. thread -> row=tid>>2, k-group=(tid&3)*4
        {
            const int lr = tid >> 2;
            const int lk = (tid & 3) * 4;
            const int gm = brow + lr;
            float4 av = make_float4(0.f, 0.f, 0.f, 0.f);
            if (gm < M) av = *(const float4*)&A[(size_t)gm * K + k0 + lk];
            if (RELU_IN) {
                av.x = fmaxf(av.x, 0.f); av.y = fmaxf(av.y, 0.f);
                av.z = fmaxf(av.z, 0.f); av.w = fmaxf(av.w, 0.f);
            }
            As[lk + 0][lr] = av.x; As[lk + 1][lr] = av.y;
            As[lk + 2][lr] = av.z; As[lk + 3][lr] = av.w;
        }
        // Load B tile: 16 k x 64 cols. thread -> k=tid>>4, col-group=(tid&15)*4
        {
            const int kr = tid >> 4;
            const int kc = (tid & 15) * 4;
            float4 bv = *(const float4*)&B[(size_t)(k0 + kr) * N + bcol + kc];
            Bs[kr][kc + 0] = bv.x; Bs[kr][kc + 1] = bv.y;
            Bs[kr][kc + 2] = bv.z; Bs[kr][kc + 3] = bv.w;
        }
        __syncthreads();
#pragma unroll
        for (int kk = 0; kk < 16; ++kk) {
            float a[4], b[4];
#pragma unroll
            for (int i = 0; i < 4; ++i) a[i] = As[kk][ty * 4 + i];
#pragma unroll
            for (int j = 0; j < 4; ++j) b[j] = Bs[kk][tx * 4 + j];
#pragma unroll
            for (int i = 0; i < 4; ++i)
#pragma unroll
                for (int j = 0; j < 4; ++j) acc[i][j] += a[i] * b[j];
        }
        __syncthreads();
    }
#pragma unroll
    for (int i = 0; i < 4; ++i) {
        const int row = brow + ty * 4 + i;
        if (row >= M) continue;
#pragma unroll
        for (int j = 0; j < 4; ++j) {
            C[(size_t)row * N + bcol + tx * 4 + j] = acc[i][j];
        }
    }
}

// ---------------- attention coefficients, layer 1 ----------------
// a_src[n,h] = dot(h1[n, h*32 .. h*32+31], att_src[h]); same for dst.
__global__ void att1_kernel(const float* __restrict__ h1,
                            const float* __restrict__ att_src,
                            const float* __restrict__ att_dst,
                            float* __restrict__ a_src,
                            float* __restrict__ a_dst, int Nn) {
    const int i = blockIdx.x * blockDim.x + threadIdx.x;
    if (i >= Nn * HEADS) return;
    const int n = i >> 3, h = i & 7;
    const float* hp = h1 + (size_t)n * F1 + h * HID;
    const float* as = att_src + h * HID;
    const float* ad = att_dst + h * HID;
    float s = 0.f, d = 0.f;
#pragma unroll
    for (int f = 0; f < HID; ++f) {
        const float v = hp[f];
        s += v * as[f];
        d += v * ad[f];
    }
    a_src[i] = s;
    a_dst[i] = d;
}

// ---------------- attention coefficients, layer 2 (1 head, 64ch) --------
__global__ void att2_kernel(const float* __restrict__ h2,
                            const float* __restrict__ att_src,
                            const float* __restrict__ att_dst,
                            float* __restrict__ a_src,
                            float* __restrict__ a_dst, int Nn) {
    const int n = blockIdx.x * blockDim.x + threadIdx.x;
    if (n >= Nn) return;
    const float* hp = h2 + (size_t)n * F2;
    float s = 0.f, d = 0.f;
#pragma unroll
    for (int f = 0; f < F2; ++f) {
        const float v = hp[f];
        s += v * att_src[f];
        d += v * att_dst[f];
    }
    a_src[n] = s;
    a_dst[n] = d;
}

// ---------------- init: out1 = b1, out = b2, denoms = 0 ----------------
__global__ void init_kernel(float* __restrict__ out1, float* __restrict__ outF,
                            float* __restrict__ denom1, float* __restrict__ denom2,
                            const float* __restrict__ b1,
                            const float* __restrict__ b2, int Nn) {
    const int i = blockIdx.x * blockDim.x + threadIdx.x;
    if (i < Nn * F1) out1[i] = b1[i & (F1 - 1)];
    if (i < Nn * F2) outF[i] = b2[i & (F2 - 1)];
    if (i < Nn * HEADS) denom1[i] = 0.f;
    if (i < Nn) denom2[i] = 0.f;
}

__device__ __forceinline__ float leaky(float v) {
    return v > 0.f ? v : NEG_SLOPE * v;
}

// ---------------- edge denom, layer 1: thread per (edge, head) ----------
__global__ void edge_denom1(const int* __restrict__ ei, int E, int Nn,
                            const float* __restrict__ a_src,
                            const float* __restrict__ a_dst,
                            float* __restrict__ denom) {
    const int i = blockIdx.x * blockDim.x + threadIdx.x;
    const int total = (E + Nn) * HEADS;
    if (i >= total) return;
    const int e = i >> 3, h = i & 7;
    int s, d;
    if (e < E) { s = ei[e]; d = ei[E + e]; } else { s = d = e - E; }
    const float val = leaky(a_src[s * HEADS + h] + a_dst[d * HEADS + h]);
    atomicAdd(&denom[d * HEADS + h], __expf(val));
}

// ---------------- edge message, layer 1: wave per edge ------------------
// lane l handles channels [4l, 4l+4); head = l >> 3.
__global__ void edge_msg1(const int* __restrict__ ei, int E, int Nn,
                          const float* __restrict__ a_src,
                          const float* __restrict__ a_dst,
                          const float* __restrict__ denom,
                          const float* __restrict__ h1,
                          float* __restrict__ out1) {
    const int edge = blockIdx.x * 4 + (threadIdx.x >> 6);
    if (edge >= E + Nn) return;
    const int lane = threadIdx.x & 63;
    int s, d;
    if (edge < E) { s = ei[edge]; d = ei[E + edge]; } else { s = d = edge - E; }
    const int h = lane >> 3;
    const float val = leaky(a_src[s * HEADS + h] + a_dst[d * HEADS + h]);
    const float alpha = __expf(val) / denom[d * HEADS + h];
    const int c = lane * 4;
    const float4 v = *(const float4*)&h1[(size_t)s * F1 + c];
    float* op = &out1[(size_t)d * F1 + c];
    atomicAdd(op + 0, alpha * v.x);
    atomicAdd(op + 1, alpha * v.y);
    atomicAdd(op + 2, alpha * v.z);
    atomicAdd(op + 3, alpha * v.w);
}

// ---------------- edge denom, layer 2: thread per edge ------------------
__global__ void edge_denom2(const int* __restrict__ ei, int E, int Nn,
                            const float* __restrict__ a_src,
                            const float* __restrict__ a_dst,
                            float* __restrict__ denom) {
    const int e = blockIdx.x * blockDim.x + threadIdx.x;
    if (e >= E + Nn) return;
    int s, d;
    if (e < E) { s = ei[e]; d = ei[E + e]; } else { s = d = e - E; }
    const float val = leaky(a_src[s] + a_dst[d]);
    atomicAdd(&denom[d], __expf(val));
}

// ---------------- edge message, layer 2: wave per edge, lane = channel --
__global__ void edge_msg2(const int* __restrict__ ei, int E, int Nn,
                          const float* __restrict__ a_src,
                          const float* __restrict__ a_dst,
                          const float* __restrict__ denom,
                          const float* __restrict__ h2,
                          float* __restrict__ outF) {
    const int edge = blockIdx.x * 4 + (threadIdx.x >> 6);
    if (edge >= E + Nn) return;
    const int c = threadIdx.x & 63;
    int s, d;
    if (edge < E) { s = ei[edge]; d = ei[E + edge]; } else { s = d = edge - E; }
    const float val = leaky(a_src[s] + a_dst[d]);
    const float alpha = __expf(val) / denom[d];
    atomicAdd(&outF[(size_t)d * F2 + c], alpha * h2[(size_t)s * F2 + c]);
}

extern "C" void kernel_launch(void* const* d_in, const int* in_sizes, int n_in,
                              void* d_out, int out_size, void* d_ws, size_t ws_size,
                              hipStream_t stream) {
    const float* x        = (const float*)d_in[0];
    const int*   ei       = (const int*)d_in[1];     // [2, E] int32
    const float* W1       = (const float*)d_in[2];   // [256,256]
    const float* att_src1 = (const float*)d_in[3];   // [8,32]
    const float* att_dst1 = (const float*)d_in[4];
    const float* b1       = (const float*)d_in[5];   // [256]
    const float* W2       = (const float*)d_in[6];   // [256,64]
    const float* att_src2 = (const float*)d_in[7];   // [1,64]
    const float* att_dst2 = (const float*)d_in[8];
    const float* b2       = (const float*)d_in[9];   // [64]
    float* out = (float*)d_out;                      // [N,64]

    const int Nn = in_sizes[0] / F1;    // 50000
    const int E  = in_sizes[1] / 2;     // 800000
    const int Etot = E + Nn;            // with self loops

    // workspace layout (floats)
    float* ws = (float*)d_ws;
    float* h1     = ws;                       // N*256
    float* out1   = h1 + (size_t)Nn * F1;     // N*256
    float* h2     = out1 + (size_t)Nn * F1;   // N*64
    float* a_src1 = h2 + (size_t)Nn * F2;     // N*8
    float* a_dst1 = a_src1 + (size_t)Nn * HEADS;
    float* denom1 = a_dst1 + (size_t)Nn * HEADS;
    float* a_src2 = denom1 + (size_t)Nn * HEADS;  // N
    float* a_dst2 = a_src2 + Nn;
    float* denom2 = a_dst2 + Nn;

    // 1) h1 = x @ W1
    {
        dim3 grid((Nn + 63) / 64, F1 / 64);
        gemm_kernel<false><<<grid, 256, 0, stream>>>(x, W1, h1, Nn, F1, F1);
    }
    // 2) attention coefficients layer 1
    att1_kernel<<<(Nn * HEADS + 255) / 256, 256, 0, stream>>>(
        h1, att_src1, att_dst1, a_src1, a_dst1, Nn);
    // 3) init out1=b1, out=b2, denoms=0
    init_kernel<<<((size_t)Nn * F1 + 255) / 256, 256, 0, stream>>>(
        out1, out, denom1, denom2, b1, b2, Nn);
    // 4) denominators layer 1
    edge_denom1<<<(Etot * HEADS + 255) / 256, 256, 0, stream>>>(
        ei, E, Nn, a_src1, a_dst1, denom1);
    // 5) messages layer 1 (wave per edge)
    edge_msg1<<<(Etot + 3) / 4, 256, 0, stream>>>(
        ei, E, Nn, a_src1, a_dst1, denom1, h1, out1);
    // 6) h2 = relu(out1) @ W2
    {
        dim3 grid((Nn + 63) / 64, F2 / 64);
        gemm_kernel<true><<<grid, 256, 0, stream>>>(out1, W2, h2, Nn, F2, F1);
    }
    // 7) attention coefficients layer 2
    att2_kernel<<<(Nn + 255) / 256, 256, 0, stream>>>(
        h2, att_src2, att_dst2, a_src2, a_dst2, Nn);
    // 8) denominators layer 2
    edge_denom2<<<(Etot + 255) / 256, 256, 0, stream>>>(
        ei, E, Nn, a_src2, a_dst2, denom2);
    // 9) messages layer 2
    edge_msg2<<<(Etot + 3) / 4, 256, 0, stream>>>(
        ei, E, Nn, a_src2, a_dst2, denom2, h2, out);
}

// Round 2
// 720.234 us; speedup vs baseline: 4.7387x; 4.7387x over previous
//
#include <hip/hip_runtime.h>
#include <hip/hip_bf16.h>

// GAT 2-layer forward. N=50000, E=800000 (+N self loops), IN=256,
// layer1: 8 heads x 32 (concat -> 256), relu, layer2: 256 -> 64, 1 head.
// Strategy: build CSR by dst on device, then gather (wave-per-node) with
// denominator fused into the same pass. No float atomics.

#define HEADS 8
#define HID 32
#define F1 256   // IN and layer-1 output width (8*32)
#define F2 64    // layer-2 output width
#define NEG_SLOPE 0.2f

// ---------------- GEMM: C[M,N] = op(A[M,K]) @ B[K,N] ----------------
template<bool RELU_IN>
__global__ void gemm_kernel(const float* __restrict__ A,
                            const float* __restrict__ B,
                            float* __restrict__ C,
                            int M, int N, int K) {
    __shared__ float As[16][65];  // [k][m]
    __shared__ float Bs[16][65];  // [k][n]
    const int tid = threadIdx.x;
    const int tx = tid & 15;
    const int ty = tid >> 4;
    const int brow = blockIdx.x * 64;
    const int bcol = blockIdx.y * 64;

    float acc[4][4] = {};

    for (int k0 = 0; k0 < K; k0 += 16) {
        {
            const int lr = tid >> 2;
            const int lk = (tid & 3) * 4;
            const int gm = brow + lr;
            float4 av = make_float4(0.f, 0.f, 0.f, 0.f);
            if (gm < M) av = *(const float4*)&A[(size_t)gm * K + k0 + lk];
            if (RELU_IN) {
                av.x = fmaxf(av.x, 0.f); av.y = fmaxf(av.y, 0.f);
                av.z = fmaxf(av.z, 0.f); av.w = fmaxf(av.w, 0.f);
            }
            As[lk + 0][lr] = av.x; As[lk + 1][lr] = av.y;
            As[lk + 2][lr] = av.z; As[lk + 3][lr] = av.w;
        }
        {
            const int kr = tid >> 4;
            const int kc = (tid & 15) * 4;
            float4 bv = *(const float4*)&B[(size_t)(k0 + kr) * N + bcol + kc];
            Bs[kr][kc + 0] = bv.x; Bs[kr][kc + 1] = bv.y;
            Bs[kr][kc + 2] = bv.z; Bs[kr][kc + 3] = bv.w;
        }
        __syncthreads();
#pragma unroll
        for (int kk = 0; kk < 16; ++kk) {
            float a[4], b[4];
#pragma unroll
            for (int i = 0; i < 4; ++i) a[i] = As[kk][ty * 4 + i];
#pragma unroll
            for (int j = 0; j < 4; ++j) b[j] = Bs[kk][tx * 4 + j];
#pragma unroll
            for (int i = 0; i < 4; ++i)
#pragma unroll
                for (int j = 0; j < 4; ++j) acc[i][j] += a[i] * b[j];
        }
        __syncthreads();
    }
#pragma unroll
    for (int i = 0; i < 4; ++i) {
        const int row = brow + ty * 4 + i;
        if (row >= M) continue;
#pragma unroll
        for (int j = 0; j < 4; ++j) {
            C[(size_t)row * N + bcol + tx * 4 + j] = acc[i][j];
        }
    }
}

// ---------------- attention coefficients ----------------
__global__ void att1_kernel(const float* __restrict__ h1,
                            const float* __restrict__ att_src,
                            const float* __restrict__ att_dst,
                            float* __restrict__ a_src,
                            float* __restrict__ a_dst, int Nn) {
    const int i = blockIdx.x * blockDim.x + threadIdx.x;
    if (i >= Nn * HEADS) return;
    const int n = i >> 3, h = i & 7;
    const float* hp = h1 + (size_t)n * F1 + h * HID;
    const float* as = att_src + h * HID;
    const float* ad = att_dst + h * HID;
    float s = 0.f, d = 0.f;
#pragma unroll
    for (int f = 0; f < HID; ++f) {
        const float v = hp[f];
        s += v * as[f];
        d += v * ad[f];
    }
    a_src[i] = s;
    a_dst[i] = d;
}

__global__ void att2_kernel(const float* __restrict__ h2,
                            const float* __restrict__ att_src,
                            const float* __restrict__ att_dst,
                            float* __restrict__ a_src,
                            float* __restrict__ a_dst, int Nn) {
    const int n = blockIdx.x * blockDim.x + threadIdx.x;
    if (n >= Nn) return;
    const float* hp = h2 + (size_t)n * F2;
    float s = 0.f, d = 0.f;
#pragma unroll
    for (int f = 0; f < F2; ++f) {
        const float v = hp[f];
        s += v * att_src[f];
        d += v * att_dst[f];
    }
    a_src[n] = s;
    a_dst[n] = d;
}

__device__ __forceinline__ float leaky(float v) {
    return v > 0.f ? v : NEG_SLOPE * v;
}

// ---------------- CSR build ----------------
__global__ void zero_deg(int* __restrict__ deg, int Nn) {
    const int i = blockIdx.x * blockDim.x + threadIdx.x;
    if (i < Nn) deg[i] = 0;
}

__global__ void hist_kernel(const int* __restrict__ ei, int E,
                            int* __restrict__ deg) {
    const int e = blockIdx.x * blockDim.x + threadIdx.x;
    if (e < E) atomicAdd(&deg[ei[E + e]], 1);
}

// single-block exclusive scan over deg -> rowptr, cursor (Nn up to ~1M ok)
__global__ __launch_bounds__(1024) void scan_kernel(
        const int* __restrict__ deg, int* __restrict__ rowptr,
        int* __restrict__ cursor, int Nn) {
    __shared__ int sums[1024];
    const int T = 1024;
    const int tid = threadIdx.x;
    const int chunk = (Nn + T - 1) / T;
    const int start = tid * chunk;
    const int end = min(start + chunk, Nn);
    int s = 0;
    for (int i = start; i < end; ++i) s += deg[i];
    sums[tid] = s;
    __syncthreads();
    for (int off = 1; off < T; off <<= 1) {
        const int v = sums[tid];
        const int add = (tid >= off) ? sums[tid - off] : 0;
        __syncthreads();
        sums[tid] = v + add;
        __syncthreads();
    }
    int offset = (tid == 0) ? 0 : sums[tid - 1];
    for (int i = start; i < end; ++i) {
        rowptr[i] = offset;
        cursor[i] = offset;
        offset += deg[i];
    }
    if (tid == T - 1) rowptr[Nn] = sums[T - 1];
}

__global__ void scatter_kernel(const int* __restrict__ ei, int E,
                               int* __restrict__ cursor,
                               int* __restrict__ csr_src) {
    const int e = blockIdx.x * blockDim.x + threadIdx.x;
    if (e >= E) return;
    const int d = ei[E + e];
    const int pos = atomicAdd(&cursor[d], 1);
    csr_src[pos] = ei[e];
}

// ---------------- layer-1 gather: one wave per dst node ----------------
// lane l: head h = l>>3, channels c = 4l..4l+3. Self-loop handled inline.
__global__ __launch_bounds__(256) void gather1_kernel(
        const int* __restrict__ rowptr, const int* __restrict__ csr_src,
        const float* __restrict__ a_src, const float* __restrict__ a_dst,
        const float* __restrict__ h1, const float* __restrict__ b1,
        float* __restrict__ out1, int Nn) {
    const int d = blockIdx.x * 4 + (threadIdx.x >> 6);
    if (d >= Nn) return;
    const int lane = threadIdx.x & 63;
    const int h = lane >> 3;
    const int c = lane * 4;

    const float adst = a_dst[d * HEADS + h];
    // self-loop
    float w = __expf(leaky(a_src[d * HEADS + h] + adst));
    float4 v = *(const float4*)&h1[(size_t)d * F1 + c];
    float denom = w;
    float ax = w * v.x, ay = w * v.y, az = w * v.z, aw = w * v.w;

    const int beg = rowptr[d], end = rowptr[d + 1];
    for (int i = beg; i < end; ++i) {
        const int s = csr_src[i];
        w = __expf(leaky(a_src[s * HEADS + h] + adst));
        v = *(const float4*)&h1[(size_t)s * F1 + c];
        denom += w;
        ax += w * v.x; ay += w * v.y; az += w * v.z; aw += w * v.w;
    }
    const float inv = 1.f / denom;
    const float4 bias = *(const float4*)&b1[c];
    float4 o;
    o.x = ax * inv + bias.x; o.y = ay * inv + bias.y;
    o.z = az * inv + bias.z; o.w = aw * inv + bias.w;
    *(float4*)&out1[(size_t)d * F1 + c] = o;
}

// ---------------- layer-2 gather: one wave per dst node, lane=channel ---
__global__ __launch_bounds__(256) void gather2_kernel(
        const int* __restrict__ rowptr, const int* __restrict__ csr_src,
        const float* __restrict__ a_src, const float* __restrict__ a_dst,
        const float* __restrict__ h2, const float* __restrict__ b2,
        float* __restrict__ out, int Nn) {
    const int d = blockIdx.x * 4 + (threadIdx.x >> 6);
    if (d >= Nn) return;
    const int c = threadIdx.x & 63;

    const float adst = a_dst[d];
    float w = __expf(leaky(a_src[d] + adst));
    float denom = w;
    float acc = w * h2[(size_t)d * F2 + c];

    const int beg = rowptr[d], end = rowptr[d + 1];
    for (int i = beg; i < end; ++i) {
        const int s = csr_src[i];
        w = __expf(leaky(a_src[s] + adst));
        denom += w;
        acc += w * h2[(size_t)s * F2 + c];
    }
    out[(size_t)d * F2 + c] = acc / denom + b2[c];
}

extern "C" void kernel_launch(void* const* d_in, const int* in_sizes, int n_in,
                              void* d_out, int out_size, void* d_ws, size_t ws_size,
                              hipStream_t stream) {
    const float* x        = (const float*)d_in[0];
    const int*   ei       = (const int*)d_in[1];     // [2, E] int32
    const float* W1       = (const float*)d_in[2];   // [256,256]
    const float* att_src1 = (const float*)d_in[3];   // [8,32]
    const float* att_dst1 = (const float*)d_in[4];
    const float* b1       = (const float*)d_in[5];   // [256]
    const float* W2       = (const float*)d_in[6];   // [256,64]
    const float* att_src2 = (const float*)d_in[7];   // [1,64]
    const float* att_dst2 = (const float*)d_in[8];
    const float* b2       = (const float*)d_in[9];   // [64]
    float* out = (float*)d_out;                      // [N,64]

    const int Nn = in_sizes[0] / F1;    // 50000
    const int E  = in_sizes[1] / 2;     // 800000

    // workspace layout (floats / ints)
    float* ws = (float*)d_ws;
    float* h1     = ws;                            // N*256
    float* out1   = h1 + (size_t)Nn * F1;          // N*256
    float* h2     = out1 + (size_t)Nn * F1;        // N*64
    float* a_src1 = h2 + (size_t)Nn * F2;          // N*8
    float* a_dst1 = a_src1 + (size_t)Nn * HEADS;   // N*8
    float* a_src2 = a_dst1 + (size_t)Nn * HEADS;   // N
    float* a_dst2 = a_src2 + Nn;                   // N
    int* deg     = (int*)(a_dst2 + Nn);            // N
    int* rowptr  = deg + Nn;                       // N+1
    int* cursor  = rowptr + Nn + 1;                // N
    int* csr_src = cursor + Nn;                    // E

    // --- CSR build (by dst) ---
    zero_deg<<<(Nn + 255) / 256, 256, 0, stream>>>(deg, Nn);
    hist_kernel<<<(E + 255) / 256, 256, 0, stream>>>(ei, E, deg);
    scan_kernel<<<1, 1024, 0, stream>>>(deg, rowptr, cursor, Nn);
    scatter_kernel<<<(E + 255) / 256, 256, 0, stream>>>(ei, E, cursor, csr_src);

    // --- layer 1 ---
    {
        dim3 grid((Nn + 63) / 64, F1 / 64);
        gemm_kernel<false><<<grid, 256, 0, stream>>>(x, W1, h1, Nn, F1, F1);
    }
    att1_kernel<<<(Nn * HEADS + 255) / 256, 256, 0, stream>>>(
        h1, att_src1, att_dst1, a_src1, a_dst1, Nn);
    gather1_kernel<<<(Nn + 3) / 4, 256, 0, stream>>>(
        rowptr, csr_src, a_src1, a_dst1, h1, b1, out1, Nn);

    // --- layer 2 ---
    {
        dim3 grid((Nn + 63) / 64, F2 / 64);
        gemm_kernel<true><<<grid, 256, 0, stream>>>(out1, W2, h2, Nn, F2, F1);
    }
    att2_kernel<<<(Nn + 255) / 256, 256, 0, stream>>>(
        h2, att_src2, att_dst2, a_src2, a_dst2, Nn);
    gather2_kernel<<<(Nn + 3) / 4, 256, 0, stream>>>(
        rowptr, csr_src, a_src2, a_dst2, h2, b2, out, Nn);
}

// Round 3
// 547.551 us; speedup vs baseline: 6.2331x; 1.3154x over previous
//
#include <hip/hip_runtime.h>
#include <hip/hip_bf16.h>

// GAT 2-layer forward. N=50000, E=800000 (+N self loops), IN=256,
// layer1: 8 heads x 32 (concat -> 256), relu, layer2: 256 -> 64, 1 head.
// Round 3: bf16 MFMA GEMMs (16x16x32), bf16 h1 for edge gather, CSR gather
// with fused softmax denominator. No float atomics.

#define HEADS 8
#define HID 32
#define F1 256   // IN and layer-1 output width (8*32)
#define F2 64    // layer-2 output width
#define NEG_SLOPE 0.2f

typedef __attribute__((ext_vector_type(8))) short bf16x8;
typedef __attribute__((ext_vector_type(4))) float f32x4;

__device__ __forceinline__ unsigned short f2b(float f) {
    union { float f; unsigned int i; } x; x.f = f;
    unsigned int r = x.i + 0x7fffu + ((x.i >> 16) & 1u);  // RNE
    return (unsigned short)(r >> 16);
}
__device__ __forceinline__ float b2f(unsigned short u) {
    union { unsigned int i; float f; } x; x.i = ((unsigned int)u) << 16;
    return x.f;
}
__device__ __forceinline__ float leaky(float v) {
    return v > 0.f ? v : NEG_SLOPE * v;
}

// ---------------- casts ----------------
__global__ void cast_x_kernel(const float* __restrict__ x,
                              unsigned short* __restrict__ xb, int total4) {
    const int i = blockIdx.x * 256 + threadIdx.x;  // 4 elems per thread
    if (i >= total4) return;
    const float4 v = ((const float4*)x)[i];
    ushort4 o;
    o.x = f2b(v.x); o.y = f2b(v.y); o.z = f2b(v.z); o.w = f2b(v.w);
    ((ushort4*)xb)[i] = o;
}

// W: [K,N] fp32 -> WT: [N,K] bf16
__global__ void cast_WT_kernel(const float* __restrict__ W,
                               unsigned short* __restrict__ WT, int K, int N) {
    const int i = blockIdx.x * 256 + threadIdx.x;
    if (i >= K * N) return;
    const int k = i / N, n = i - k * N;
    WT[(size_t)n * K + k] = f2b(W[i]);
}

// ---------------- MFMA GEMM: C[M,N] = A[M,K] @ BT[N,K]^T ----------------
// BM=128, BN templated (128 or 64), BK=32, 256 threads (4 waves).
// A, BT bf16; C bf16 or fp32.  K multiple of 32; N multiple of BN.
template<int BN, bool OUT_BF16>
__global__ __launch_bounds__(256) void mfma_gemm(
        const unsigned short* __restrict__ A,
        const unsigned short* __restrict__ BT,
        void* __restrict__ C, int M, int N, int K) {
    constexpr int BM = 128, BK = 32;
    __shared__ unsigned short As[BM * BK];
    __shared__ unsigned short Bs[BN * BK];
    const int tid = threadIdx.x;
    const int wave = tid >> 6, lane = tid & 63;
    const int quad = lane >> 4, l16 = lane & 15;
    const int brow = blockIdx.x * BM;
    const int bcol = blockIdx.y * BN;

    constexpr int MI = (BN == 128) ? 4 : 2;   // m-subtiles per wave
    constexpr int NJ = 4;                     // n-subtiles per wave
    const int wm = (BN == 128) ? (wave & 1) * 64 : wave * 32;
    const int wn = (BN == 128) ? (wave >> 1) * 64 : 0;

    f32x4 acc[MI][NJ] = {};

    for (int k0 = 0; k0 < K; k0 += BK) {
        // stage A tile [BM][BK]
#pragma unroll
        for (int it = 0; it < (BM * BK) / (256 * 8); ++it) {
            const int idx = it * 256 + tid;
            const int r = idx >> 2;
            const int kk = (idx & 3) * 8;
            const int gr = brow + r;
            uint4 v = make_uint4(0u, 0u, 0u, 0u);
            if (gr < M) v = *(const uint4*)&A[(size_t)gr * K + k0 + kk];
            *(uint4*)&As[r * BK + kk] = v;
        }
        // stage B tile [BN][BK] (BT rows are n)
#pragma unroll
        for (int it = 0; it < (BN * BK) / (256 * 8); ++it) {
            const int idx = it * 256 + tid;
            const int r = idx >> 2;
            const int kk = (idx & 3) * 8;
            const uint4 v = *(const uint4*)&BT[(size_t)(bcol + r) * K + k0 + kk];
            *(uint4*)&Bs[r * BK + kk] = v;
        }
        __syncthreads();
        bf16x8 af[MI], bfr[NJ];
#pragma unroll
        for (int i = 0; i < MI; ++i)
            af[i] = *(const bf16x8*)&As[(wm + i * 16 + l16) * BK + quad * 8];
#pragma unroll
        for (int j = 0; j < NJ; ++j)
            bfr[j] = *(const bf16x8*)&Bs[(wn + j * 16 + l16) * BK + quad * 8];
#pragma unroll
        for (int i = 0; i < MI; ++i)
#pragma unroll
            for (int j = 0; j < NJ; ++j)
                acc[i][j] = __builtin_amdgcn_mfma_f32_16x16x32_bf16(
                    af[i], bfr[j], acc[i][j], 0, 0, 0);
        __syncthreads();
    }
    // epilogue: C/D layout col=lane&15, row=quad*4+reg
#pragma unroll
    for (int i = 0; i < MI; ++i) {
#pragma unroll
        for (int r = 0; r < 4; ++r) {
            const int row = brow + wm + i * 16 + quad * 4 + r;
            if (row >= M) continue;
#pragma unroll
            for (int j = 0; j < NJ; ++j) {
                const int col = bcol + wn + j * 16 + l16;
                const float v = acc[i][j][r];
                if (OUT_BF16)
                    ((unsigned short*)C)[(size_t)row * N + col] = f2b(v);
                else
                    ((float*)C)[(size_t)row * N + col] = v;
            }
        }
    }
}

// ---------------- attention coefficients ----------------
__global__ void att1_kernel(const unsigned short* __restrict__ h1b,
                            const float* __restrict__ att_src,
                            const float* __restrict__ att_dst,
                            float* __restrict__ a_src,
                            float* __restrict__ a_dst, int Nn) {
    const int i = blockIdx.x * blockDim.x + threadIdx.x;
    if (i >= Nn * HEADS) return;
    const int n = i >> 3, h = i & 7;
    const unsigned short* hp = h1b + (size_t)n * F1 + h * HID;
    const float* as = att_src + h * HID;
    const float* ad = att_dst + h * HID;
    float s = 0.f, d = 0.f;
#pragma unroll
    for (int f = 0; f < HID; ++f) {
        const float v = b2f(hp[f]);
        s += v * as[f];
        d += v * ad[f];
    }
    a_src[i] = s;
    a_dst[i] = d;
}

__global__ void att2_kernel(const float* __restrict__ h2,
                            const float* __restrict__ att_src,
                            const float* __restrict__ att_dst,
                            float* __restrict__ a_src,
                            float* __restrict__ a_dst, int Nn) {
    const int n = blockIdx.x * blockDim.x + threadIdx.x;
    if (n >= Nn) return;
    const float* hp = h2 + (size_t)n * F2;
    float s = 0.f, d = 0.f;
#pragma unroll
    for (int f = 0; f < F2; ++f) {
        const float v = hp[f];
        s += v * att_src[f];
        d += v * att_dst[f];
    }
    a_src[n] = s;
    a_dst[n] = d;
}

// ---------------- CSR build ----------------
__global__ void zero_deg(int* __restrict__ deg, int Nn) {
    const int i = blockIdx.x * blockDim.x + threadIdx.x;
    if (i < Nn) deg[i] = 0;
}

__global__ void hist_kernel(const int* __restrict__ ei, int E,
                            int* __restrict__ deg) {
    const int e = blockIdx.x * blockDim.x + threadIdx.x;
    if (e < E) atomicAdd(&deg[ei[E + e]], 1);
}

__global__ __launch_bounds__(1024) void scan_kernel(
        const int* __restrict__ deg, int* __restrict__ rowptr,
        int* __restrict__ cursor, int Nn) {
    __shared__ int sums[1024];
    const int T = 1024;
    const int tid = threadIdx.x;
    const int chunk = (Nn + T - 1) / T;
    const int start = tid * chunk;
    const int end = min(start + chunk, Nn);
    int s = 0;
    for (int i = start; i < end; ++i) s += deg[i];
    sums[tid] = s;
    __syncthreads();
    for (int off = 1; off < T; off <<= 1) {
        const int v = sums[tid];
        const int add = (tid >= off) ? sums[tid - off] : 0;
        __syncthreads();
        sums[tid] = v + add;
        __syncthreads();
    }
    int offset = (tid == 0) ? 0 : sums[tid - 1];
    for (int i = start; i < end; ++i) {
        rowptr[i] = offset;
        cursor[i] = offset;
        offset += deg[i];
    }
    if (tid == T - 1) rowptr[Nn] = sums[T - 1];
}

__global__ void scatter_kernel(const int* __restrict__ ei, int E,
                               int* __restrict__ cursor,
                               int* __restrict__ csr_src) {
    const int e = blockIdx.x * blockDim.x + threadIdx.x;
    if (e >= E) return;
    const int d = ei[E + e];
    const int pos = atomicAdd(&cursor[d], 1);
    csr_src[pos] = ei[e];
}

// ---------------- layer-1 gather: one wave per dst node ----------------
// lane l: head h = l>>3, channels c = 4l..4l+3. Emits bf16 relu(out+bias).
__global__ __launch_bounds__(256) void gather1_kernel(
        const int* __restrict__ rowptr, const int* __restrict__ csr_src,
        const float* __restrict__ a_src, const float* __restrict__ a_dst,
        const unsigned short* __restrict__ h1b, const float* __restrict__ b1,
        unsigned short* __restrict__ out1b, int Nn) {
    const int d = blockIdx.x * 4 + (threadIdx.x >> 6);
    if (d >= Nn) return;
    const int lane = threadIdx.x & 63;
    const int h = lane >> 3;
    const int c = lane * 4;

    const float adst = a_dst[d * HEADS + h];
    // self-loop
    float w = __expf(leaky(a_src[d * HEADS + h] + adst));
    ushort4 v = *(const ushort4*)&h1b[(size_t)d * F1 + c];
    float denom = w;
    float ax = w * b2f(v.x), ay = w * b2f(v.y);
    float az = w * b2f(v.z), aw = w * b2f(v.w);

    const int beg = rowptr[d], end = rowptr[d + 1];
    for (int i = beg; i < end; ++i) {
        const int s = csr_src[i];
        w = __expf(leaky(a_src[s * HEADS + h] + adst));
        v = *(const ushort4*)&h1b[(size_t)s * F1 + c];
        denom += w;
        ax += w * b2f(v.x); ay += w * b2f(v.y);
        az += w * b2f(v.z); aw += w * b2f(v.w);
    }
    const float inv = 1.f / denom;
    ushort4 o;
    o.x = f2b(fmaxf(ax * inv + b1[c + 0], 0.f));
    o.y = f2b(fmaxf(ay * inv + b1[c + 1], 0.f));
    o.z = f2b(fmaxf(az * inv + b1[c + 2], 0.f));
    o.w = f2b(fmaxf(aw * inv + b1[c + 3], 0.f));
    *(ushort4*)&out1b[(size_t)d * F1 + c] = o;
}

// ---------------- layer-2 gather: one wave per dst node, lane=channel ---
__global__ __launch_bounds__(256) void gather2_kernel(
        const int* __restrict__ rowptr, const int* __restrict__ csr_src,
        const float* __restrict__ a_src, const float* __restrict__ a_dst,
        const float* __restrict__ h2, const float* __restrict__ b2,
        float* __restrict__ out, int Nn) {
    const int d = blockIdx.x * 4 + (threadIdx.x >> 6);
    if (d >= Nn) return;
    const int c = threadIdx.x & 63;

    const float adst = a_dst[d];
    float w = __expf(leaky(a_src[d] + adst));
    float denom = w;
    float acc = w * h2[(size_t)d * F2 + c];

    const int beg = rowptr[d], end = rowptr[d + 1];
    for (int i = beg; i < end; ++i) {
        const int s = csr_src[i];
        w = __expf(leaky(a_src[s] + adst));
        denom += w;
        acc += w * h2[(size_t)s * F2 + c];
    }
    out[(size_t)d * F2 + c] = acc / denom + b2[c];
}

extern "C" void kernel_launch(void* const* d_in, const int* in_sizes, int n_in,
                              void* d_out, int out_size, void* d_ws, size_t ws_size,
                              hipStream_t stream) {
    const float* x        = (const float*)d_in[0];
    const int*   ei       = (const int*)d_in[1];     // [2, E]
    const float* W1       = (const float*)d_in[2];   // [256,256]
    const float* att_src1 = (const float*)d_in[3];   // [8,32]
    const float* att_dst1 = (const float*)d_in[4];
    const float* b1       = (const float*)d_in[5];   // [256]
    const float* W2       = (const float*)d_in[6];   // [256,64]
    const float* att_src2 = (const float*)d_in[7];   // [1,64]
    const float* att_dst2 = (const float*)d_in[8];
    const float* b2       = (const float*)d_in[9];   // [64]
    float* out = (float*)d_out;                      // [N,64]

    const int Nn = in_sizes[0] / F1;    // 50000
    const int E  = in_sizes[1] / 2;     // 800000

    // workspace layout — wide-aligned arrays first
    char* p = (char*)d_ws;
    unsigned short* xb    = (unsigned short*)p; p += (size_t)Nn * F1 * 2;  // bf16 x
    unsigned short* h1b   = (unsigned short*)p; p += (size_t)Nn * F1 * 2;  // bf16 h1
    unsigned short* out1b = (unsigned short*)p; p += (size_t)Nn * F1 * 2;  // bf16 relu(out1)
    unsigned short* W1T   = (unsigned short*)p; p += (size_t)F1 * F1 * 2;
    unsigned short* W2T   = (unsigned short*)p; p += (size_t)F2 * F1 * 2;
    float* h2     = (float*)p; p += (size_t)Nn * F2 * 4;
    float* a_src1 = (float*)p; p += (size_t)Nn * HEADS * 4;
    float* a_dst1 = (float*)p; p += (size_t)Nn * HEADS * 4;
    float* a_src2 = (float*)p; p += (size_t)Nn * 4;
    float* a_dst2 = (float*)p; p += (size_t)Nn * 4;
    int* deg     = (int*)p; p += (size_t)Nn * 4;
    int* rowptr  = (int*)p; p += (size_t)(Nn + 1) * 4;
    int* cursor  = (int*)p; p += (size_t)Nn * 4;
    int* csr_src = (int*)p; p += (size_t)E * 4;

    // --- casts ---
    cast_x_kernel<<<((Nn * F1 / 4) + 255) / 256, 256, 0, stream>>>(
        x, xb, Nn * F1 / 4);
    cast_WT_kernel<<<(F1 * F1 + 255) / 256, 256, 0, stream>>>(W1, W1T, F1, F1);
    cast_WT_kernel<<<(F1 * F2 + 255) / 256, 256, 0, stream>>>(W2, W2T, F1, F2);

    // --- CSR build (by dst) ---
    zero_deg<<<(Nn + 255) / 256, 256, 0, stream>>>(deg, Nn);
    hist_kernel<<<(E + 255) / 256, 256, 0, stream>>>(ei, E, deg);
    scan_kernel<<<1, 1024, 0, stream>>>(deg, rowptr, cursor, Nn);
    scatter_kernel<<<(E + 255) / 256, 256, 0, stream>>>(ei, E, cursor, csr_src);

    // --- layer 1 ---
    {
        dim3 grid((Nn + 127) / 128, F1 / 128);
        mfma_gemm<128, true><<<grid, 256, 0, stream>>>(xb, W1T, h1b, Nn, F1, F1);
    }
    att1_kernel<<<(Nn * HEADS + 255) / 256, 256, 0, stream>>>(
        h1b, att_src1, att_dst1, a_src1, a_dst1, Nn);
    gather1_kernel<<<(Nn + 3) / 4, 256, 0, stream>>>(
        rowptr, csr_src, a_src1, a_dst1, h1b, b1, out1b, Nn);

    // --- layer 2 ---
    {
        dim3 grid((Nn + 127) / 128, F2 / 64);
        mfma_gemm<64, false><<<grid, 256, 0, stream>>>(out1b, W2T, h2, Nn, F2, F1);
    }
    att2_kernel<<<(Nn + 255) / 256, 256, 0, stream>>>(
        h2, att_src2, att_dst2, a_src2, a_dst2, Nn);
    gather2_kernel<<<(Nn + 3) / 4, 256, 0, stream>>>(
        rowptr, csr_src, a_src2, a_dst2, h2, b2, out, Nn);
}

// Round 4
// 434.903 us; speedup vs baseline: 7.8476x; 1.2590x over previous
//
#include <hip/hip_runtime.h>
#include <hip/hip_bf16.h>

// GAT 2-layer forward. N=50000, E=800000 (+N self loops), IN=256,
// layer1: 8 heads x 32 (concat -> 256), relu, layer2: 256 -> 64, 1 head.
// Round 4: hierarchical 3-phase CSR scan (was: 110us single-block scan).
// bf16 MFMA GEMMs, CSR gather with fused softmax denom, no float atomics.

#define HEADS 8
#define HID 32
#define F1 256   // IN and layer-1 output width (8*32)
#define F2 64    // layer-2 output width
#define NEG_SLOPE 0.2f
#define SCAN_CHUNK 1024   // nodes per scan block (256 thr x 4)

typedef __attribute__((ext_vector_type(8))) short bf16x8;
typedef __attribute__((ext_vector_type(4))) float f32x4;

__device__ __forceinline__ unsigned short f2b(float f) {
    union { float f; unsigned int i; } x; x.f = f;
    unsigned int r = x.i + 0x7fffu + ((x.i >> 16) & 1u);  // RNE
    return (unsigned short)(r >> 16);
}
__device__ __forceinline__ float b2f(unsigned short u) {
    union { unsigned int i; float f; } x; x.i = ((unsigned int)u) << 16;
    return x.f;
}
__device__ __forceinline__ float leaky(float v) {
    return v > 0.f ? v : NEG_SLOPE * v;
}

// ---------------- casts ----------------
__global__ void cast_x_kernel(const float* __restrict__ x,
                              unsigned short* __restrict__ xb, int total4) {
    const int i = blockIdx.x * 256 + threadIdx.x;  // 4 elems per thread
    if (i >= total4) return;
    const float4 v = ((const float4*)x)[i];
    ushort4 o;
    o.x = f2b(v.x); o.y = f2b(v.y); o.z = f2b(v.z); o.w = f2b(v.w);
    ((ushort4*)xb)[i] = o;
}

// W: [K,N] fp32 -> WT: [N,K] bf16
__global__ void cast_WT_kernel(const float* __restrict__ W,
                               unsigned short* __restrict__ WT, int K, int N) {
    const int i = blockIdx.x * 256 + threadIdx.x;
    if (i >= K * N) return;
    const int k = i / N, n = i - k * N;
    WT[(size_t)n * K + k] = f2b(W[i]);
}

// ---------------- MFMA GEMM: C[M,N] = A[M,K] @ BT[N,K]^T ----------------
template<int BN, bool OUT_BF16>
__global__ __launch_bounds__(256) void mfma_gemm(
        const unsigned short* __restrict__ A,
        const unsigned short* __restrict__ BT,
        void* __restrict__ C, int M, int N, int K) {
    constexpr int BM = 128, BK = 32;
    __shared__ unsigned short As[BM * BK];
    __shared__ unsigned short Bs[BN * BK];
    const int tid = threadIdx.x;
    const int wave = tid >> 6, lane = tid & 63;
    const int quad = lane >> 4, l16 = lane & 15;
    const int brow = blockIdx.x * BM;
    const int bcol = blockIdx.y * BN;

    constexpr int MI = (BN == 128) ? 4 : 2;
    constexpr int NJ = 4;
    const int wm = (BN == 128) ? (wave & 1) * 64 : wave * 32;
    const int wn = (BN == 128) ? (wave >> 1) * 64 : 0;

    f32x4 acc[MI][NJ] = {};

    for (int k0 = 0; k0 < K; k0 += BK) {
#pragma unroll
        for (int it = 0; it < (BM * BK) / (256 * 8); ++it) {
            const int idx = it * 256 + tid;
            const int r = idx >> 2;
            const int kk = (idx & 3) * 8;
            const int gr = brow + r;
            uint4 v = make_uint4(0u, 0u, 0u, 0u);
            if (gr < M) v = *(const uint4*)&A[(size_t)gr * K + k0 + kk];
            *(uint4*)&As[r * BK + kk] = v;
        }
#pragma unroll
        for (int it = 0; it < (BN * BK) / (256 * 8); ++it) {
            const int idx = it * 256 + tid;
            const int r = idx >> 2;
            const int kk = (idx & 3) * 8;
            const uint4 v = *(const uint4*)&BT[(size_t)(bcol + r) * K + k0 + kk];
            *(uint4*)&Bs[r * BK + kk] = v;
        }
        __syncthreads();
        bf16x8 af[MI], bfr[NJ];
#pragma unroll
        for (int i = 0; i < MI; ++i)
            af[i] = *(const bf16x8*)&As[(wm + i * 16 + l16) * BK + quad * 8];
#pragma unroll
        for (int j = 0; j < NJ; ++j)
            bfr[j] = *(const bf16x8*)&Bs[(wn + j * 16 + l16) * BK + quad * 8];
#pragma unroll
        for (int i = 0; i < MI; ++i)
#pragma unroll
            for (int j = 0; j < NJ; ++j)
                acc[i][j] = __builtin_amdgcn_mfma_f32_16x16x32_bf16(
                    af[i], bfr[j], acc[i][j], 0, 0, 0);
        __syncthreads();
    }
#pragma unroll
    for (int i = 0; i < MI; ++i) {
#pragma unroll
        for (int r = 0; r < 4; ++r) {
            const int row = brow + wm + i * 16 + quad * 4 + r;
            if (row >= M) continue;
#pragma unroll
            for (int j = 0; j < NJ; ++j) {
                const int col = bcol + wn + j * 16 + l16;
                const float v = acc[i][j][r];
                if (OUT_BF16)
                    ((unsigned short*)C)[(size_t)row * N + col] = f2b(v);
                else
                    ((float*)C)[(size_t)row * N + col] = v;
            }
        }
    }
}

// ---------------- attention coefficients ----------------
__global__ void att1_kernel(const unsigned short* __restrict__ h1b,
                            const float* __restrict__ att_src,
                            const float* __restrict__ att_dst,
                            float* __restrict__ a_src,
                            float* __restrict__ a_dst, int Nn) {
    const int i = blockIdx.x * blockDim.x + threadIdx.x;
    if (i >= Nn * HEADS) return;
    const int n = i >> 3, h = i & 7;
    const unsigned short* hp = h1b + (size_t)n * F1 + h * HID;
    const float* as = att_src + h * HID;
    const float* ad = att_dst + h * HID;
    float s = 0.f, d = 0.f;
#pragma unroll
    for (int f = 0; f < HID; ++f) {
        const float v = b2f(hp[f]);
        s += v * as[f];
        d += v * ad[f];
    }
    a_src[i] = s;
    a_dst[i] = d;
}

__global__ void att2_kernel(const float* __restrict__ h2,
                            const float* __restrict__ att_src,
                            const float* __restrict__ att_dst,
                            float* __restrict__ a_src,
                            float* __restrict__ a_dst, int Nn) {
    const int n = blockIdx.x * blockDim.x + threadIdx.x;
    if (n >= Nn) return;
    const float* hp = h2 + (size_t)n * F2;
    float s = 0.f, d = 0.f;
#pragma unroll
    for (int f = 0; f < F2; ++f) {
        const float v = hp[f];
        s += v * att_src[f];
        d += v * att_dst[f];
    }
    a_src[n] = s;
    a_dst[n] = d;
}

// ---------------- CSR build ----------------
__global__ void zero_deg(int* __restrict__ deg, int Nn) {
    const int i = blockIdx.x * blockDim.x + threadIdx.x;
    if (i < Nn) deg[i] = 0;
}

__global__ void hist_kernel(const int* __restrict__ ei, int E,
                            int* __restrict__ deg) {
    const int e = blockIdx.x * blockDim.x + threadIdx.x;
    if (e < E) atomicAdd(&deg[ei[E + e]], 1);
}

// --- 3-phase hierarchical exclusive scan over deg[Nn] ---
// phase 1: per-block (1024-node chunk) sums
__global__ __launch_bounds__(256) void scan_bsum(const int* __restrict__ deg,
                                                 int* __restrict__ bsum, int Nn) {
    const int base = blockIdx.x * SCAN_CHUNK + threadIdx.x * 4;
    int s = 0;
#pragma unroll
    for (int j = 0; j < 4; ++j) {
        const int i = base + j;
        if (i < Nn) s += deg[i];
    }
#pragma unroll
    for (int off = 32; off > 0; off >>= 1) s += __shfl_down(s, off, 64);
    __shared__ int ws[4];
    if ((threadIdx.x & 63) == 0) ws[threadIdx.x >> 6] = s;
    __syncthreads();
    if (threadIdx.x == 0) bsum[blockIdx.x] = ws[0] + ws[1] + ws[2] + ws[3];
}

// phase 2: single block scans the <=256 block sums -> exclusive offsets
__global__ __launch_bounds__(256) void scan_boff(const int* __restrict__ bsum,
                                                 int* __restrict__ boff,
                                                 int* __restrict__ rowptr,
                                                 int B, int Nn) {
    __shared__ int sums[256];
    const int tid = threadIdx.x;
    const int v = (tid < B) ? bsum[tid] : 0;
    sums[tid] = v;
    __syncthreads();
    for (int off = 1; off < 256; off <<= 1) {
        const int cur = sums[tid];
        const int add = (tid >= off) ? sums[tid - off] : 0;
        __syncthreads();
        sums[tid] = cur + add;
        __syncthreads();
    }
    if (tid < B) boff[tid] = sums[tid] - v;   // exclusive
    if (tid == 255) rowptr[Nn] = sums[255];   // total
}

// phase 3: per-block local exclusive scan + global offset -> rowptr/cursor
__global__ __launch_bounds__(256) void scan_write(const int* __restrict__ deg,
                                                  const int* __restrict__ boff,
                                                  int* __restrict__ rowptr,
                                                  int* __restrict__ cursor, int Nn) {
    const int tid = threadIdx.x;
    const int base = blockIdx.x * SCAN_CHUNK + tid * 4;
    int v[4];
    int s = 0;
#pragma unroll
    for (int j = 0; j < 4; ++j) {
        const int i = base + j;
        v[j] = (i < Nn) ? deg[i] : 0;
        s += v[j];
    }
    __shared__ int sums[256];
    sums[tid] = s;
    __syncthreads();
    for (int off = 1; off < 256; off <<= 1) {
        const int cur = sums[tid];
        const int add = (tid >= off) ? sums[tid - off] : 0;
        __syncthreads();
        sums[tid] = cur + add;
        __syncthreads();
    }
    int off = boff[blockIdx.x] + sums[tid] - s;  // exclusive prefix
#pragma unroll
    for (int j = 0; j < 4; ++j) {
        const int i = base + j;
        if (i < Nn) {
            rowptr[i] = off;
            cursor[i] = off;
            off += v[j];
        }
    }
}

__global__ void scatter_kernel(const int* __restrict__ ei, int E,
                               int* __restrict__ cursor,
                               int* __restrict__ csr_src) {
    const int e = blockIdx.x * blockDim.x + threadIdx.x;
    if (e >= E) return;
    const int d = ei[E + e];
    const int pos = atomicAdd(&cursor[d], 1);
    csr_src[pos] = ei[e];
}

// ---------------- layer-1 gather: one wave per dst node ----------------
__global__ __launch_bounds__(256) void gather1_kernel(
        const int* __restrict__ rowptr, const int* __restrict__ csr_src,
        const float* __restrict__ a_src, const float* __restrict__ a_dst,
        const unsigned short* __restrict__ h1b, const float* __restrict__ b1,
        unsigned short* __restrict__ out1b, int Nn) {
    const int d = blockIdx.x * 4 + (threadIdx.x >> 6);
    if (d >= Nn) return;
    const int lane = threadIdx.x & 63;
    const int h = lane >> 3;
    const int c = lane * 4;

    const float adst = a_dst[d * HEADS + h];
    float w = __expf(leaky(a_src[d * HEADS + h] + adst));
    ushort4 v = *(const ushort4*)&h1b[(size_t)d * F1 + c];
    float denom = w;
    float ax = w * b2f(v.x), ay = w * b2f(v.y);
    float az = w * b2f(v.z), aw = w * b2f(v.w);

    const int beg = rowptr[d], end = rowptr[d + 1];
    for (int i = beg; i < end; ++i) {
        const int s = csr_src[i];
        w = __expf(leaky(a_src[s * HEADS + h] + adst));
        v = *(const ushort4*)&h1b[(size_t)s * F1 + c];
        denom += w;
        ax += w * b2f(v.x); ay += w * b2f(v.y);
        az += w * b2f(v.z); aw += w * b2f(v.w);
    }
    const float inv = 1.f / denom;
    ushort4 o;
    o.x = f2b(fmaxf(ax * inv + b1[c + 0], 0.f));
    o.y = f2b(fmaxf(ay * inv + b1[c + 1], 0.f));
    o.z = f2b(fmaxf(az * inv + b1[c + 2], 0.f));
    o.w = f2b(fmaxf(aw * inv + b1[c + 3], 0.f));
    *(ushort4*)&out1b[(size_t)d * F1 + c] = o;
}

// ---------------- layer-2 gather ----------------
__global__ __launch_bounds__(256) void gather2_kernel(
        const int* __restrict__ rowptr, const int* __restrict__ csr_src,
        const float* __restrict__ a_src, const float* __restrict__ a_dst,
        const float* __restrict__ h2, const float* __restrict__ b2,
        float* __restrict__ out, int Nn) {
    const int d = blockIdx.x * 4 + (threadIdx.x >> 6);
    if (d >= Nn) return;
    const int c = threadIdx.x & 63;

    const float adst = a_dst[d];
    float w = __expf(leaky(a_src[d] + adst));
    float denom = w;
    float acc = w * h2[(size_t)d * F2 + c];

    const int beg = rowptr[d], end = rowptr[d + 1];
    for (int i = beg; i < end; ++i) {
        const int s = csr_src[i];
        w = __expf(leaky(a_src[s] + adst));
        denom += w;
        acc += w * h2[(size_t)s * F2 + c];
    }
    out[(size_t)d * F2 + c] = acc / denom + b2[c];
}

extern "C" void kernel_launch(void* const* d_in, const int* in_sizes, int n_in,
                              void* d_out, int out_size, void* d_ws, size_t ws_size,
                              hipStream_t stream) {
    const float* x        = (const float*)d_in[0];
    const int*   ei       = (const int*)d_in[1];     // [2, E]
    const float* W1       = (const float*)d_in[2];   // [256,256]
    const float* att_src1 = (const float*)d_in[3];   // [8,32]
    const float* att_dst1 = (const float*)d_in[4];
    const float* b1       = (const float*)d_in[5];   // [256]
    const float* W2       = (const float*)d_in[6];   // [256,64]
    const float* att_src2 = (const float*)d_in[7];   // [1,64]
    const float* att_dst2 = (const float*)d_in[8];
    const float* b2       = (const float*)d_in[9];   // [64]
    float* out = (float*)d_out;                      // [N,64]

    const int Nn = in_sizes[0] / F1;    // 50000
    const int E  = in_sizes[1] / 2;     // 800000
    const int NB = (Nn + SCAN_CHUNK - 1) / SCAN_CHUNK;  // scan blocks (<=256)

    // workspace layout — wide-aligned arrays first
    char* p = (char*)d_ws;
    unsigned short* xb    = (unsigned short*)p; p += (size_t)Nn * F1 * 2;
    unsigned short* h1b   = (unsigned short*)p; p += (size_t)Nn * F1 * 2;
    unsigned short* out1b = (unsigned short*)p; p += (size_t)Nn * F1 * 2;
    unsigned short* W1T   = (unsigned short*)p; p += (size_t)F1 * F1 * 2;
    unsigned short* W2T   = (unsigned short*)p; p += (size_t)F2 * F1 * 2;
    float* h2     = (float*)p; p += (size_t)Nn * F2 * 4;
    float* a_src1 = (float*)p; p += (size_t)Nn * HEADS * 4;
    float* a_dst1 = (float*)p; p += (size_t)Nn * HEADS * 4;
    float* a_src2 = (float*)p; p += (size_t)Nn * 4;
    float* a_dst2 = (float*)p; p += (size_t)Nn * 4;
    int* deg     = (int*)p; p += (size_t)Nn * 4;
    int* rowptr  = (int*)p; p += (size_t)(Nn + 1) * 4;
    int* cursor  = (int*)p; p += (size_t)Nn * 4;
    int* bsum    = (int*)p; p += 256 * 4;
    int* boff    = (int*)p; p += 256 * 4;
    int* csr_src = (int*)p; p += (size_t)E * 4;

    // --- casts ---
    cast_x_kernel<<<((Nn * F1 / 4) + 255) / 256, 256, 0, stream>>>(
        x, xb, Nn * F1 / 4);
    cast_WT_kernel<<<(F1 * F1 + 255) / 256, 256, 0, stream>>>(W1, W1T, F1, F1);
    cast_WT_kernel<<<(F1 * F2 + 255) / 256, 256, 0, stream>>>(W2, W2T, F1, F2);

    // --- CSR build (by dst) ---
    zero_deg<<<(Nn + 255) / 256, 256, 0, stream>>>(deg, Nn);
    hist_kernel<<<(E + 255) / 256, 256, 0, stream>>>(ei, E, deg);
    scan_bsum<<<NB, 256, 0, stream>>>(deg, bsum, Nn);
    scan_boff<<<1, 256, 0, stream>>>(bsum, boff, rowptr, NB, Nn);
    scan_write<<<NB, 256, 0, stream>>>(deg, boff, rowptr, cursor, Nn);
    scatter_kernel<<<(E + 255) / 256, 256, 0, stream>>>(ei, E, cursor, csr_src);

    // --- layer 1 ---
    {
        dim3 grid((Nn + 127) / 128, F1 / 128);
        mfma_gemm<128, true><<<grid, 256, 0, stream>>>(xb, W1T, h1b, Nn, F1, F1);
    }
    att1_kernel<<<(Nn * HEADS + 255) / 256, 256, 0, stream>>>(
        h1b, att_src1, att_dst1, a_src1, a_dst1, Nn);
    gather1_kernel<<<(Nn + 3) / 4, 256, 0, stream>>>(
        rowptr, csr_src, a_src1, a_dst1, h1b, b1, out1b, Nn);

    // --- layer 2 ---
    {
        dim3 grid((Nn + 127) / 128, F2 / 64);
        mfma_gemm<64, false><<<grid, 256, 0, stream>>>(out1b, W2T, h2, Nn, F2, F1);
    }
    att2_kernel<<<(Nn + 255) / 256, 256, 0, stream>>>(
        h2, att_src2, att_dst2, a_src2, a_dst2, Nn);
    gather2_kernel<<<(Nn + 3) / 4, 256, 0, stream>>>(
        rowptr, csr_src, a_src2, a_dst2, h2, b2, out, Nn);
}

// Round 5
// 375.536 us; speedup vs baseline: 9.0882x; 1.1581x over previous
//
#include <hip/hip_runtime.h>
#include <hip/hip_bf16.h>

// GAT 2-layer forward. N=50000, E=800000 (+N self loops), IN=256,
// layer1: 8 heads x 32 (concat -> 256), relu, layer2: 256 -> 64, 1 head.
// Round 5: unroll-4 edge loops in gathers for memory-level parallelism
// (gather1 was latency-bound: 31% HBM, 34% VALU, serial dependent loads).

#define HEADS 8
#define HID 32
#define F1 256   // IN and layer-1 output width (8*32)
#define F2 64    // layer-2 output width
#define NEG_SLOPE 0.2f
#define SCAN_CHUNK 1024   // nodes per scan block (256 thr x 4)

typedef __attribute__((ext_vector_type(8))) short bf16x8;
typedef __attribute__((ext_vector_type(4))) float f32x4;

__device__ __forceinline__ unsigned short f2b(float f) {
    union { float f; unsigned int i; } x; x.f = f;
    unsigned int r = x.i + 0x7fffu + ((x.i >> 16) & 1u);  // RNE
    return (unsigned short)(r >> 16);
}
__device__ __forceinline__ float b2f(unsigned short u) {
    union { unsigned int i; float f; } x; x.i = ((unsigned int)u) << 16;
    return x.f;
}
__device__ __forceinline__ float leaky(float v) {
    return v > 0.f ? v : NEG_SLOPE * v;
}

// ---------------- casts ----------------
__global__ void cast_x_kernel(const float* __restrict__ x,
                              unsigned short* __restrict__ xb, int total4) {
    const int i = blockIdx.x * 256 + threadIdx.x;  // 4 elems per thread
    if (i >= total4) return;
    const float4 v = ((const float4*)x)[i];
    ushort4 o;
    o.x = f2b(v.x); o.y = f2b(v.y); o.z = f2b(v.z); o.w = f2b(v.w);
    ((ushort4*)xb)[i] = o;
}

// W: [K,N] fp32 -> WT: [N,K] bf16
__global__ void cast_WT_kernel(const float* __restrict__ W,
                               unsigned short* __restrict__ WT, int K, int N) {
    const int i = blockIdx.x * 256 + threadIdx.x;
    if (i >= K * N) return;
    const int k = i / N, n = i - k * N;
    WT[(size_t)n * K + k] = f2b(W[i]);
}

// ---------------- MFMA GEMM: C[M,N] = A[M,K] @ BT[N,K]^T ----------------
template<int BN, bool OUT_BF16>
__global__ __launch_bounds__(256) void mfma_gemm(
        const unsigned short* __restrict__ A,
        const unsigned short* __restrict__ BT,
        void* __restrict__ C, int M, int N, int K) {
    constexpr int BM = 128, BK = 32;
    __shared__ unsigned short As[BM * BK];
    __shared__ unsigned short Bs[BN * BK];
    const int tid = threadIdx.x;
    const int wave = tid >> 6, lane = tid & 63;
    const int quad = lane >> 4, l16 = lane & 15;
    const int brow = blockIdx.x * BM;
    const int bcol = blockIdx.y * BN;

    constexpr int MI = (BN == 128) ? 4 : 2;
    constexpr int NJ = 4;
    const int wm = (BN == 128) ? (wave & 1) * 64 : wave * 32;
    const int wn = (BN == 128) ? (wave >> 1) * 64 : 0;

    f32x4 acc[MI][NJ] = {};

    for (int k0 = 0; k0 < K; k0 += BK) {
#pragma unroll
        for (int it = 0; it < (BM * BK) / (256 * 8); ++it) {
            const int idx = it * 256 + tid;
            const int r = idx >> 2;
            const int kk = (idx & 3) * 8;
            const int gr = brow + r;
            uint4 v = make_uint4(0u, 0u, 0u, 0u);
            if (gr < M) v = *(const uint4*)&A[(size_t)gr * K + k0 + kk];
            *(uint4*)&As[r * BK + kk] = v;
        }
#pragma unroll
        for (int it = 0; it < (BN * BK) / (256 * 8); ++it) {
            const int idx = it * 256 + tid;
            const int r = idx >> 2;
            const int kk = (idx & 3) * 8;
            const uint4 v = *(const uint4*)&BT[(size_t)(bcol + r) * K + k0 + kk];
            *(uint4*)&Bs[r * BK + kk] = v;
        }
        __syncthreads();
        bf16x8 af[MI], bfr[NJ];
#pragma unroll
        for (int i = 0; i < MI; ++i)
            af[i] = *(const bf16x8*)&As[(wm + i * 16 + l16) * BK + quad * 8];
#pragma unroll
        for (int j = 0; j < NJ; ++j)
            bfr[j] = *(const bf16x8*)&Bs[(wn + j * 16 + l16) * BK + quad * 8];
#pragma unroll
        for (int i = 0; i < MI; ++i)
#pragma unroll
            for (int j = 0; j < NJ; ++j)
                acc[i][j] = __builtin_amdgcn_mfma_f32_16x16x32_bf16(
                    af[i], bfr[j], acc[i][j], 0, 0, 0);
        __syncthreads();
    }
#pragma unroll
    for (int i = 0; i < MI; ++i) {
#pragma unroll
        for (int r = 0; r < 4; ++r) {
            const int row = brow + wm + i * 16 + quad * 4 + r;
            if (row >= M) continue;
#pragma unroll
            for (int j = 0; j < NJ; ++j) {
                const int col = bcol + wn + j * 16 + l16;
                const float v = acc[i][j][r];
                if (OUT_BF16)
                    ((unsigned short*)C)[(size_t)row * N + col] = f2b(v);
                else
                    ((float*)C)[(size_t)row * N + col] = v;
            }
        }
    }
}

// ---------------- attention coefficients ----------------
__global__ void att1_kernel(const unsigned short* __restrict__ h1b,
                            const float* __restrict__ att_src,
                            const float* __restrict__ att_dst,
                            float* __restrict__ a_src,
                            float* __restrict__ a_dst, int Nn) {
    const int i = blockIdx.x * blockDim.x + threadIdx.x;
    if (i >= Nn * HEADS) return;
    const int n = i >> 3, h = i & 7;
    const unsigned short* hp = h1b + (size_t)n * F1 + h * HID;
    const float* as = att_src + h * HID;
    const float* ad = att_dst + h * HID;
    float s = 0.f, d = 0.f;
#pragma unroll
    for (int f = 0; f < HID; ++f) {
        const float v = b2f(hp[f]);
        s += v * as[f];
        d += v * ad[f];
    }
    a_src[i] = s;
    a_dst[i] = d;
}

__global__ void att2_kernel(const float* __restrict__ h2,
                            const float* __restrict__ att_src,
                            const float* __restrict__ att_dst,
                            float* __restrict__ a_src,
                            float* __restrict__ a_dst, int Nn) {
    const int n = blockIdx.x * blockDim.x + threadIdx.x;
    if (n >= Nn) return;
    const float* hp = h2 + (size_t)n * F2;
    float s = 0.f, d = 0.f;
#pragma unroll
    for (int f = 0; f < F2; ++f) {
        const float v = hp[f];
        s += v * att_src[f];
        d += v * att_dst[f];
    }
    a_src[n] = s;
    a_dst[n] = d;
}

// ---------------- CSR build ----------------
__global__ void zero_deg(int* __restrict__ deg, int Nn) {
    const int i = blockIdx.x * blockDim.x + threadIdx.x;
    if (i < Nn) deg[i] = 0;
}

__global__ void hist_kernel(const int* __restrict__ ei, int E,
                            int* __restrict__ deg) {
    const int e = blockIdx.x * blockDim.x + threadIdx.x;
    if (e < E) atomicAdd(&deg[ei[E + e]], 1);
}

// --- 3-phase hierarchical exclusive scan over deg[Nn] ---
__global__ __launch_bounds__(256) void scan_bsum(const int* __restrict__ deg,
                                                 int* __restrict__ bsum, int Nn) {
    const int base = blockIdx.x * SCAN_CHUNK + threadIdx.x * 4;
    int s = 0;
#pragma unroll
    for (int j = 0; j < 4; ++j) {
        const int i = base + j;
        if (i < Nn) s += deg[i];
    }
#pragma unroll
    for (int off = 32; off > 0; off >>= 1) s += __shfl_down(s, off, 64);
    __shared__ int ws[4];
    if ((threadIdx.x & 63) == 0) ws[threadIdx.x >> 6] = s;
    __syncthreads();
    if (threadIdx.x == 0) bsum[blockIdx.x] = ws[0] + ws[1] + ws[2] + ws[3];
}

__global__ __launch_bounds__(256) void scan_boff(const int* __restrict__ bsum,
                                                 int* __restrict__ boff,
                                                 int* __restrict__ rowptr,
                                                 int B, int Nn) {
    __shared__ int sums[256];
    const int tid = threadIdx.x;
    const int v = (tid < B) ? bsum[tid] : 0;
    sums[tid] = v;
    __syncthreads();
    for (int off = 1; off < 256; off <<= 1) {
        const int cur = sums[tid];
        const int add = (tid >= off) ? sums[tid - off] : 0;
        __syncthreads();
        sums[tid] = cur + add;
        __syncthreads();
    }
    if (tid < B) boff[tid] = sums[tid] - v;   // exclusive
    if (tid == 255) rowptr[Nn] = sums[255];   // total
}

__global__ __launch_bounds__(256) void scan_write(const int* __restrict__ deg,
                                                  const int* __restrict__ boff,
                                                  int* __restrict__ rowptr,
                                                  int* __restrict__ cursor, int Nn) {
    const int tid = threadIdx.x;
    const int base = blockIdx.x * SCAN_CHUNK + tid * 4;
    int v[4];
    int s = 0;
#pragma unroll
    for (int j = 0; j < 4; ++j) {
        const int i = base + j;
        v[j] = (i < Nn) ? deg[i] : 0;
        s += v[j];
    }
    __shared__ int sums[256];
    sums[tid] = s;
    __syncthreads();
    for (int off = 1; off < 256; off <<= 1) {
        const int cur = sums[tid];
        const int add = (tid >= off) ? sums[tid - off] : 0;
        __syncthreads();
        sums[tid] = cur + add;
        __syncthreads();
    }
    int off = boff[blockIdx.x] + sums[tid] - s;  // exclusive prefix
#pragma unroll
    for (int j = 0; j < 4; ++j) {
        const int i = base + j;
        if (i < Nn) {
            rowptr[i] = off;
            cursor[i] = off;
            off += v[j];
        }
    }
}

__global__ void scatter_kernel(const int* __restrict__ ei, int E,
                               int* __restrict__ cursor,
                               int* __restrict__ csr_src) {
    const int e = blockIdx.x * blockDim.x + threadIdx.x;
    if (e >= E) return;
    const int d = ei[E + e];
    const int pos = atomicAdd(&cursor[d], 1);
    csr_src[pos] = ei[e];
}

// ---------------- layer-1 gather: one wave per dst node ----------------
// lane l: head h = l>>3, channels c = 4l..4l+3. Unroll-4 edge loop for MLP.
__global__ __launch_bounds__(256) void gather1_kernel(
        const int* __restrict__ rowptr, const int* __restrict__ csr_src,
        const float* __restrict__ a_src, const float* __restrict__ a_dst,
        const unsigned short* __restrict__ h1b, const float* __restrict__ b1,
        unsigned short* __restrict__ out1b, int Nn) {
    const int d = blockIdx.x * 4 + (threadIdx.x >> 6);
    if (d >= Nn) return;
    const int lane = threadIdx.x & 63;
    const int h = lane >> 3;
    const int c = lane * 4;

    const float adst = a_dst[d * HEADS + h];
    // self-loop
    float w = __expf(leaky(a_src[d * HEADS + h] + adst));
    ushort4 v = *(const ushort4*)&h1b[(size_t)d * F1 + c];
    float denom = w;
    float ax = w * b2f(v.x), ay = w * b2f(v.y);
    float az = w * b2f(v.z), aw = w * b2f(v.w);

    const int beg = rowptr[d], end = rowptr[d + 1];
    int i = beg;
    for (; i + 4 <= end; i += 4) {
        const int s0 = csr_src[i + 0];
        const int s1 = csr_src[i + 1];
        const int s2 = csr_src[i + 2];
        const int s3 = csr_src[i + 3];
        const float e0 = a_src[s0 * HEADS + h];
        const float e1 = a_src[s1 * HEADS + h];
        const float e2 = a_src[s2 * HEADS + h];
        const float e3 = a_src[s3 * HEADS + h];
        const ushort4 v0 = *(const ushort4*)&h1b[(size_t)s0 * F1 + c];
        const ushort4 v1 = *(const ushort4*)&h1b[(size_t)s1 * F1 + c];
        const ushort4 v2 = *(const ushort4*)&h1b[(size_t)s2 * F1 + c];
        const ushort4 v3 = *(const ushort4*)&h1b[(size_t)s3 * F1 + c];
        const float w0 = __expf(leaky(e0 + adst));
        const float w1 = __expf(leaky(e1 + adst));
        const float w2 = __expf(leaky(e2 + adst));
        const float w3 = __expf(leaky(e3 + adst));
        denom += (w0 + w1) + (w2 + w3);
        ax += w0 * b2f(v0.x) + w1 * b2f(v1.x) + w2 * b2f(v2.x) + w3 * b2f(v3.x);
        ay += w0 * b2f(v0.y) + w1 * b2f(v1.y) + w2 * b2f(v2.y) + w3 * b2f(v3.y);
        az += w0 * b2f(v0.z) + w1 * b2f(v1.z) + w2 * b2f(v2.z) + w3 * b2f(v3.z);
        aw += w0 * b2f(v0.w) + w1 * b2f(v1.w) + w2 * b2f(v2.w) + w3 * b2f(v3.w);
    }
    for (; i < end; ++i) {
        const int s = csr_src[i];
        w = __expf(leaky(a_src[s * HEADS + h] + adst));
        v = *(const ushort4*)&h1b[(size_t)s * F1 + c];
        denom += w;
        ax += w * b2f(v.x); ay += w * b2f(v.y);
        az += w * b2f(v.z); aw += w * b2f(v.w);
    }
    const float inv = 1.f / denom;
    ushort4 o;
    o.x = f2b(fmaxf(ax * inv + b1[c + 0], 0.f));
    o.y = f2b(fmaxf(ay * inv + b1[c + 1], 0.f));
    o.z = f2b(fmaxf(az * inv + b1[c + 2], 0.f));
    o.w = f2b(fmaxf(aw * inv + b1[c + 3], 0.f));
    *(ushort4*)&out1b[(size_t)d * F1 + c] = o;
}

// ---------------- layer-2 gather: wave per node, lane = channel ---------
__global__ __launch_bounds__(256) void gather2_kernel(
        const int* __restrict__ rowptr, const int* __restrict__ csr_src,
        const float* __restrict__ a_src, const float* __restrict__ a_dst,
        const float* __restrict__ h2, const float* __restrict__ b2,
        float* __restrict__ out, int Nn) {
    const int d = blockIdx.x * 4 + (threadIdx.x >> 6);
    if (d >= Nn) return;
    const int c = threadIdx.x & 63;

    const float adst = a_dst[d];
    float w = __expf(leaky(a_src[d] + adst));
    float denom = w;
    float acc = w * h2[(size_t)d * F2 + c];

    const int beg = rowptr[d], end = rowptr[d + 1];
    int i = beg;
    for (; i + 4 <= end; i += 4) {
        const int s0 = csr_src[i + 0];
        const int s1 = csr_src[i + 1];
        const int s2 = csr_src[i + 2];
        const int s3 = csr_src[i + 3];
        const float e0 = a_src[s0];
        const float e1 = a_src[s1];
        const float e2 = a_src[s2];
        const float e3 = a_src[s3];
        const float g0 = h2[(size_t)s0 * F2 + c];
        const float g1 = h2[(size_t)s1 * F2 + c];
        const float g2 = h2[(size_t)s2 * F2 + c];
        const float g3 = h2[(size_t)s3 * F2 + c];
        const float w0 = __expf(leaky(e0 + adst));
        const float w1 = __expf(leaky(e1 + adst));
        const float w2 = __expf(leaky(e2 + adst));
        const float w3 = __expf(leaky(e3 + adst));
        denom += (w0 + w1) + (w2 + w3);
        acc += w0 * g0 + w1 * g1 + w2 * g2 + w3 * g3;
    }
    for (; i < end; ++i) {
        const int s = csr_src[i];
        w = __expf(leaky(a_src[s] + adst));
        denom += w;
        acc += w * h2[(size_t)s * F2 + c];
    }
    out[(size_t)d * F2 + c] = acc / denom + b2[c];
}

extern "C" void kernel_launch(void* const* d_in, const int* in_sizes, int n_in,
                              void* d_out, int out_size, void* d_ws, size_t ws_size,
                              hipStream_t stream) {
    const float* x        = (const float*)d_in[0];
    const int*   ei       = (const int*)d_in[1];     // [2, E]
    const float* W1       = (const float*)d_in[2];   // [256,256]
    const float* att_src1 = (const float*)d_in[3];   // [8,32]
    const float* att_dst1 = (const float*)d_in[4];
    const float* b1       = (const float*)d_in[5];   // [256]
    const float* W2       = (const float*)d_in[6];   // [256,64]
    const float* att_src2 = (const float*)d_in[7];   // [1,64]
    const float* att_dst2 = (const float*)d_in[8];
    const float* b2       = (const float*)d_in[9];   // [64]
    float* out = (float*)d_out;                      // [N,64]

    const int Nn = in_sizes[0] / F1;    // 50000
    const int E  = in_sizes[1] / 2;     // 800000
    const int NB = (Nn + SCAN_CHUNK - 1) / SCAN_CHUNK;  // scan blocks (<=256)

    // workspace layout — wide-aligned arrays first
    char* p = (char*)d_ws;
    unsigned short* xb    = (unsigned short*)p; p += (size_t)Nn * F1 * 2;
    unsigned short* h1b   = (unsigned short*)p; p += (size_t)Nn * F1 * 2;
    unsigned short* out1b = (unsigned short*)p; p += (size_t)Nn * F1 * 2;
    unsigned short* W1T   = (unsigned short*)p; p += (size_t)F1 * F1 * 2;
    unsigned short* W2T   = (unsigned short*)p; p += (size_t)F2 * F1 * 2;
    float* h2     = (float*)p; p += (size_t)Nn * F2 * 4;
    float* a_src1 = (float*)p; p += (size_t)Nn * HEADS * 4;
    float* a_dst1 = (float*)p; p += (size_t)Nn * HEADS * 4;
    float* a_src2 = (float*)p; p += (size_t)Nn * 4;
    float* a_dst2 = (float*)p; p += (size_t)Nn * 4;
    int* deg     = (int*)p; p += (size_t)Nn * 4;
    int* rowptr  = (int*)p; p += (size_t)(Nn + 1) * 4;
    int* cursor  = (int*)p; p += (size_t)Nn * 4;
    int* bsum    = (int*)p; p += 256 * 4;
    int* boff    = (int*)p; p += 256 * 4;
    int* csr_src = (int*)p; p += (size_t)E * 4;

    // --- casts ---
    cast_x_kernel<<<((Nn * F1 / 4) + 255) / 256, 256, 0, stream>>>(
        x, xb, Nn * F1 / 4);
    cast_WT_kernel<<<(F1 * F1 + 255) / 256, 256, 0, stream>>>(W1, W1T, F1, F1);
    cast_WT_kernel<<<(F1 * F2 + 255) / 256, 256, 0, stream>>>(W2, W2T, F1, F2);

    // --- CSR build (by dst) ---
    zero_deg<<<(Nn + 255) / 256, 256, 0, stream>>>(deg, Nn);
    hist_kernel<<<(E + 255) / 256, 256, 0, stream>>>(ei, E, deg);
    scan_bsum<<<NB, 256, 0, stream>>>(deg, bsum, Nn);
    scan_boff<<<1, 256, 0, stream>>>(bsum, boff, rowptr, NB, Nn);
    scan_write<<<NB, 256, 0, stream>>>(deg, boff, rowptr, cursor, Nn);
    scatter_kernel<<<(E + 255) / 256, 256, 0, stream>>>(ei, E, cursor, csr_src);

    // --- layer 1 ---
    {
        dim3 grid((Nn + 127) / 128, F1 / 128);
        mfma_gemm<128, true><<<grid, 256, 0, stream>>>(xb, W1T, h1b, Nn, F1, F1);
    }
    att1_kernel<<<(Nn * HEADS + 255) / 256, 256, 0, stream>>>(
        h1b, att_src1, att_dst1, a_src1, a_dst1, Nn);
    gather1_kernel<<<(Nn + 3) / 4, 256, 0, stream>>>(
        rowptr, csr_src, a_src1, a_dst1, h1b, b1, out1b, Nn);

    // --- layer 2 ---
    {
        dim3 grid((Nn + 127) / 128, F2 / 64);
        mfma_gemm<64, false><<<grid, 256, 0, stream>>>(out1b, W2T, h2, Nn, F2, F1);
    }
    att2_kernel<<<(Nn + 255) / 256, 256, 0, stream>>>(
        h2, att_src2, att_dst2, a_src2, a_dst2, Nn);
    gather2_kernel<<<(Nn + 3) / 4, 256, 0, stream>>>(
        rowptr, csr_src, a_src2, a_dst2, h2, b2, out, Nn);
}

// Round 6
// 351.559 us; speedup vs baseline: 9.7080x; 1.0682x over previous
//
#include <hip/hip_runtime.h>
#include <hip/hip_bf16.h>

// GAT 2-layer forward. N=50000, E=800000 (+N self loops), IN=256,
// layer1: 8 heads x 32 (concat -> 256), relu, layer2: 256 -> 64, 1 head.
// Round 6: gather1 unroll-8 (MLP), h2 in bf16 (halve gather2 traffic),
// cast_x fused into GEMM1 A-staging, setup kernels merged.

#define HEADS 8
#define HID 32
#define F1 256   // IN and layer-1 output width (8*32)
#define F2 64    // layer-2 output width
#define NEG_SLOPE 0.2f
#define SCAN_CHUNK 1024   // nodes per scan block (256 thr x 4)

typedef __attribute__((ext_vector_type(8))) short bf16x8;
typedef __attribute__((ext_vector_type(4))) float f32x4;

__device__ __forceinline__ unsigned short f2b(float f) {
    union { float f; unsigned int i; } x; x.f = f;
    unsigned int r = x.i + 0x7fffu + ((x.i >> 16) & 1u);  // RNE
    return (unsigned short)(r >> 16);
}
__device__ __forceinline__ float b2f(unsigned short u) {
    union { unsigned int i; float f; } x; x.i = ((unsigned int)u) << 16;
    return x.f;
}
__device__ __forceinline__ float leaky(float v) {
    return v > 0.f ? v : NEG_SLOPE * v;
}

// ---------------- setup: W1T, W2T casts + deg zero (merged) -------------
__global__ void setup_kernel(const float* __restrict__ W1,
                             const float* __restrict__ W2,
                             unsigned short* __restrict__ W1T,
                             unsigned short* __restrict__ W2T,
                             int* __restrict__ deg, int Nn) {
    const int i = blockIdx.x * 256 + threadIdx.x;
    if (i < F1 * F1) {                       // W1 [F1,F1] -> W1T [n][k]
        const int k = i >> 8, n = i & (F1 - 1);
        W1T[(size_t)n * F1 + k] = f2b(W1[i]);
    } else if (i < F1 * F1 + F1 * F2) {      // W2 [F1,F2] -> W2T [n][k]
        const int j = i - F1 * F1;
        const int k = j >> 6, n = j & (F2 - 1);
        W2T[(size_t)n * F1 + k] = f2b(W2[j]);
    } else if (i < F1 * F1 + F1 * F2 + Nn) {
        deg[i - F1 * F1 - F1 * F2] = 0;
    }
}

// ---------------- MFMA GEMM: C[M,N] = A[M,K] @ BT[N,K]^T ----------------
// A bf16 or fp32 (cast fused in staging); BT bf16; C bf16 or fp32.
template<int BN, bool A_FP32, bool OUT_BF16>
__global__ __launch_bounds__(256) void mfma_gemm(
        const void* __restrict__ A,
        const unsigned short* __restrict__ BT,
        void* __restrict__ C, int M, int N, int K) {
    constexpr int BM = 128, BK = 32;
    __shared__ unsigned short As[BM * BK];
    __shared__ unsigned short Bs[BN * BK];
    const int tid = threadIdx.x;
    const int wave = tid >> 6, lane = tid & 63;
    const int quad = lane >> 4, l16 = lane & 15;
    const int brow = blockIdx.x * BM;
    const int bcol = blockIdx.y * BN;

    constexpr int MI = (BN == 128) ? 4 : 2;
    constexpr int NJ = 4;
    const int wm = (BN == 128) ? (wave & 1) * 64 : wave * 32;
    const int wn = (BN == 128) ? (wave >> 1) * 64 : 0;

    f32x4 acc[MI][NJ] = {};

    for (int k0 = 0; k0 < K; k0 += BK) {
#pragma unroll
        for (int it = 0; it < (BM * BK) / (256 * 8); ++it) {
            const int idx = it * 256 + tid;
            const int r = idx >> 2;
            const int kk = (idx & 3) * 8;
            const int gr = brow + r;
            if (A_FP32) {
                const float* Af = (const float*)A;
                float4 a0 = make_float4(0.f, 0.f, 0.f, 0.f);
                float4 a1 = make_float4(0.f, 0.f, 0.f, 0.f);
                if (gr < M) {
                    a0 = *(const float4*)&Af[(size_t)gr * K + k0 + kk];
                    a1 = *(const float4*)&Af[(size_t)gr * K + k0 + kk + 4];
                }
                ushort4 lo, hi;
                lo.x = f2b(a0.x); lo.y = f2b(a0.y); lo.z = f2b(a0.z); lo.w = f2b(a0.w);
                hi.x = f2b(a1.x); hi.y = f2b(a1.y); hi.z = f2b(a1.z); hi.w = f2b(a1.w);
                *(ushort4*)&As[r * BK + kk] = lo;
                *(ushort4*)&As[r * BK + kk + 4] = hi;
            } else {
                const unsigned short* Ab = (const unsigned short*)A;
                uint4 v = make_uint4(0u, 0u, 0u, 0u);
                if (gr < M) v = *(const uint4*)&Ab[(size_t)gr * K + k0 + kk];
                *(uint4*)&As[r * BK + kk] = v;
            }
        }
#pragma unroll
        for (int it = 0; it < (BN * BK) / (256 * 8); ++it) {
            const int idx = it * 256 + tid;
            const int r = idx >> 2;
            const int kk = (idx & 3) * 8;
            const uint4 v = *(const uint4*)&BT[(size_t)(bcol + r) * K + k0 + kk];
            *(uint4*)&Bs[r * BK + kk] = v;
        }
        __syncthreads();
        bf16x8 af[MI], bfr[NJ];
#pragma unroll
        for (int i = 0; i < MI; ++i)
            af[i] = *(const bf16x8*)&As[(wm + i * 16 + l16) * BK + quad * 8];
#pragma unroll
        for (int j = 0; j < NJ; ++j)
            bfr[j] = *(const bf16x8*)&Bs[(wn + j * 16 + l16) * BK + quad * 8];
#pragma unroll
        for (int i = 0; i < MI; ++i)
#pragma unroll
            for (int j = 0; j < NJ; ++j)
                acc[i][j] = __builtin_amdgcn_mfma_f32_16x16x32_bf16(
                    af[i], bfr[j], acc[i][j], 0, 0, 0);
        __syncthreads();
    }
#pragma unroll
    for (int i = 0; i < MI; ++i) {
#pragma unroll
        for (int r = 0; r < 4; ++r) {
            const int row = brow + wm + i * 16 + quad * 4 + r;
            if (row >= M) continue;
#pragma unroll
            for (int j = 0; j < NJ; ++j) {
                const int col = bcol + wn + j * 16 + l16;
                const float v = acc[i][j][r];
                if (OUT_BF16)
                    ((unsigned short*)C)[(size_t)row * N + col] = f2b(v);
                else
                    ((float*)C)[(size_t)row * N + col] = v;
            }
        }
    }
}

// ---------------- attention coefficients ----------------
__global__ void att1_kernel(const unsigned short* __restrict__ h1b,
                            const float* __restrict__ att_src,
                            const float* __restrict__ att_dst,
                            float* __restrict__ a_src,
                            float* __restrict__ a_dst, int Nn) {
    const int i = blockIdx.x * blockDim.x + threadIdx.x;
    if (i >= Nn * HEADS) return;
    const int n = i >> 3, h = i & 7;
    const unsigned short* hp = h1b + (size_t)n * F1 + h * HID;
    const float* as = att_src + h * HID;
    const float* ad = att_dst + h * HID;
    float s = 0.f, d = 0.f;
#pragma unroll
    for (int f = 0; f < HID; ++f) {
        const float v = b2f(hp[f]);
        s += v * as[f];
        d += v * ad[f];
    }
    a_src[i] = s;
    a_dst[i] = d;
}

__global__ void att2_kernel(const unsigned short* __restrict__ h2b,
                            const float* __restrict__ att_src,
                            const float* __restrict__ att_dst,
                            float* __restrict__ a_src,
                            float* __restrict__ a_dst, int Nn) {
    const int n = blockIdx.x * blockDim.x + threadIdx.x;
    if (n >= Nn) return;
    const unsigned short* hp = h2b + (size_t)n * F2;
    float s = 0.f, d = 0.f;
#pragma unroll
    for (int f = 0; f < F2; ++f) {
        const float v = b2f(hp[f]);
        s += v * att_src[f];
        d += v * att_dst[f];
    }
    a_src[n] = s;
    a_dst[n] = d;
}

// ---------------- CSR build ----------------
__global__ void hist_kernel(const int* __restrict__ ei, int E,
                            int* __restrict__ deg) {
    const int e = blockIdx.x * blockDim.x + threadIdx.x;
    if (e < E) atomicAdd(&deg[ei[E + e]], 1);
}

__global__ __launch_bounds__(256) void scan_bsum(const int* __restrict__ deg,
                                                 int* __restrict__ bsum, int Nn) {
    const int base = blockIdx.x * SCAN_CHUNK + threadIdx.x * 4;
    int s = 0;
#pragma unroll
    for (int j = 0; j < 4; ++j) {
        const int i = base + j;
        if (i < Nn) s += deg[i];
    }
#pragma unroll
    for (int off = 32; off > 0; off >>= 1) s += __shfl_down(s, off, 64);
    __shared__ int ws[4];
    if ((threadIdx.x & 63) == 0) ws[threadIdx.x >> 6] = s;
    __syncthreads();
    if (threadIdx.x == 0) bsum[blockIdx.x] = ws[0] + ws[1] + ws[2] + ws[3];
}

__global__ __launch_bounds__(256) void scan_boff(const int* __restrict__ bsum,
                                                 int* __restrict__ boff,
                                                 int* __restrict__ rowptr,
                                                 int B, int Nn) {
    __shared__ int sums[256];
    const int tid = threadIdx.x;
    const int v = (tid < B) ? bsum[tid] : 0;
    sums[tid] = v;
    __syncthreads();
    for (int off = 1; off < 256; off <<= 1) {
        const int cur = sums[tid];
        const int add = (tid >= off) ? sums[tid - off] : 0;
        __syncthreads();
        sums[tid] = cur + add;
        __syncthreads();
    }
    if (tid < B) boff[tid] = sums[tid] - v;   // exclusive
    if (tid == 255) rowptr[Nn] = sums[255];   // total
}

__global__ __launch_bounds__(256) void scan_write(const int* __restrict__ deg,
                                                  const int* __restrict__ boff,
                                                  int* __restrict__ rowptr,
                                                  int* __restrict__ cursor, int Nn) {
    const int tid = threadIdx.x;
    const int base = blockIdx.x * SCAN_CHUNK + tid * 4;
    int v[4];
    int s = 0;
#pragma unroll
    for (int j = 0; j < 4; ++j) {
        const int i = base + j;
        v[j] = (i < Nn) ? deg[i] : 0;
        s += v[j];
    }
    __shared__ int sums[256];
    sums[tid] = s;
    __syncthreads();
    for (int off = 1; off < 256; off <<= 1) {
        const int cur = sums[tid];
        const int add = (tid >= off) ? sums[tid - off] : 0;
        __syncthreads();
        sums[tid] = cur + add;
        __syncthreads();
    }
    int off = boff[blockIdx.x] + sums[tid] - s;  // exclusive prefix
#pragma unroll
    for (int j = 0; j < 4; ++j) {
        const int i = base + j;
        if (i < Nn) {
            rowptr[i] = off;
            cursor[i] = off;
            off += v[j];
        }
    }
}

__global__ void scatter_kernel(const int* __restrict__ ei, int E,
                               int* __restrict__ cursor,
                               int* __restrict__ csr_src) {
    const int e = blockIdx.x * blockDim.x + threadIdx.x;
    if (e >= E) return;
    const int d = ei[E + e];
    const int pos = atomicAdd(&cursor[d], 1);
    csr_src[pos] = ei[e];
}

// ---------------- layer-1 gather: one wave per dst node ----------------
// lane l: head h = l>>3, channels c = 4l..4l+3. Unroll-8 edge loop (MLP).
__global__ __launch_bounds__(256) void gather1_kernel(
        const int* __restrict__ rowptr, const int* __restrict__ csr_src,
        const float* __restrict__ a_src, const float* __restrict__ a_dst,
        const unsigned short* __restrict__ h1b, const float* __restrict__ b1,
        unsigned short* __restrict__ out1b, int Nn) {
    const int d = blockIdx.x * 4 + (threadIdx.x >> 6);
    if (d >= Nn) return;
    const int lane = threadIdx.x & 63;
    const int h = lane >> 3;
    const int c = lane * 4;

    const float adst = a_dst[d * HEADS + h];
    // self-loop
    float w = __expf(leaky(a_src[d * HEADS + h] + adst));
    ushort4 v = *(const ushort4*)&h1b[(size_t)d * F1 + c];
    float denom = w;
    float ax = w * b2f(v.x), ay = w * b2f(v.y);
    float az = w * b2f(v.z), aw = w * b2f(v.w);

    const int beg = rowptr[d], end = rowptr[d + 1];
    int i = beg;
    for (; i + 8 <= end; i += 8) {
        int s[8];
        float e[8];
        ushort4 vv[8];
#pragma unroll
        for (int j = 0; j < 8; ++j) s[j] = csr_src[i + j];
#pragma unroll
        for (int j = 0; j < 8; ++j) e[j] = a_src[s[j] * HEADS + h];
#pragma unroll
        for (int j = 0; j < 8; ++j)
            vv[j] = *(const ushort4*)&h1b[(size_t)s[j] * F1 + c];
#pragma unroll
        for (int j = 0; j < 8; ++j) {
            const float wj = __expf(leaky(e[j] + adst));
            denom += wj;
            ax += wj * b2f(vv[j].x); ay += wj * b2f(vv[j].y);
            az += wj * b2f(vv[j].z); aw += wj * b2f(vv[j].w);
        }
    }
    for (; i < end; ++i) {
        const int s = csr_src[i];
        w = __expf(leaky(a_src[s * HEADS + h] + adst));
        v = *(const ushort4*)&h1b[(size_t)s * F1 + c];
        denom += w;
        ax += w * b2f(v.x); ay += w * b2f(v.y);
        az += w * b2f(v.z); aw += w * b2f(v.w);
    }
    const float inv = 1.f / denom;
    ushort4 o;
    o.x = f2b(fmaxf(ax * inv + b1[c + 0], 0.f));
    o.y = f2b(fmaxf(ay * inv + b1[c + 1], 0.f));
    o.z = f2b(fmaxf(az * inv + b1[c + 2], 0.f));
    o.w = f2b(fmaxf(aw * inv + b1[c + 3], 0.f));
    *(ushort4*)&out1b[(size_t)d * F1 + c] = o;
}

// ---------------- layer-2 gather: wave per node, lane = channel ---------
__global__ __launch_bounds__(256) void gather2_kernel(
        const int* __restrict__ rowptr, const int* __restrict__ csr_src,
        const float* __restrict__ a_src, const float* __restrict__ a_dst,
        const unsigned short* __restrict__ h2b, const float* __restrict__ b2,
        float* __restrict__ out, int Nn) {
    const int d = blockIdx.x * 4 + (threadIdx.x >> 6);
    if (d >= Nn) return;
    const int c = threadIdx.x & 63;

    const float adst = a_dst[d];
    float w = __expf(leaky(a_src[d] + adst));
    float denom = w;
    float acc = w * b2f(h2b[(size_t)d * F2 + c]);

    const int beg = rowptr[d], end = rowptr[d + 1];
    int i = beg;
    for (; i + 8 <= end; i += 8) {
        int s[8];
        float e[8];
        unsigned short g[8];
#pragma unroll
        for (int j = 0; j < 8; ++j) s[j] = csr_src[i + j];
#pragma unroll
        for (int j = 0; j < 8; ++j) e[j] = a_src[s[j]];
#pragma unroll
        for (int j = 0; j < 8; ++j) g[j] = h2b[(size_t)s[j] * F2 + c];
#pragma unroll
        for (int j = 0; j < 8; ++j) {
            const float wj = __expf(leaky(e[j] + adst));
            denom += wj;
            acc += wj * b2f(g[j]);
        }
    }
    for (; i < end; ++i) {
        const int s = csr_src[i];
        w = __expf(leaky(a_src[s] + adst));
        denom += w;
        acc += w * b2f(h2b[(size_t)s * F2 + c]);
    }
    out[(size_t)d * F2 + c] = acc / denom + b2[c];
}

extern "C" void kernel_launch(void* const* d_in, const int* in_sizes, int n_in,
                              void* d_out, int out_size, void* d_ws, size_t ws_size,
                              hipStream_t stream) {
    const float* x        = (const float*)d_in[0];
    const int*   ei       = (const int*)d_in[1];     // [2, E]
    const float* W1       = (const float*)d_in[2];   // [256,256]
    const float* att_src1 = (const float*)d_in[3];   // [8,32]
    const float* att_dst1 = (const float*)d_in[4];
    const float* b1       = (const float*)d_in[5];   // [256]
    const float* W2       = (const float*)d_in[6];   // [256,64]
    const float* att_src2 = (const float*)d_in[7];   // [1,64]
    const float* att_dst2 = (const float*)d_in[8];
    const float* b2       = (const float*)d_in[9];   // [64]
    float* out = (float*)d_out;                      // [N,64]

    const int Nn = in_sizes[0] / F1;    // 50000
    const int E  = in_sizes[1] / 2;     // 800000
    const int NB = (Nn + SCAN_CHUNK - 1) / SCAN_CHUNK;  // scan blocks (<=256)

    // workspace layout — wide-aligned arrays first
    char* p = (char*)d_ws;
    unsigned short* h1b   = (unsigned short*)p; p += (size_t)Nn * F1 * 2;
    unsigned short* out1b = (unsigned short*)p; p += (size_t)Nn * F1 * 2;
    unsigned short* W1T   = (unsigned short*)p; p += (size_t)F1 * F1 * 2;
    unsigned short* W2T   = (unsigned short*)p; p += (size_t)F2 * F1 * 2;
    unsigned short* h2b   = (unsigned short*)p; p += (size_t)Nn * F2 * 2;
    float* a_src1 = (float*)p; p += (size_t)Nn * HEADS * 4;
    float* a_dst1 = (float*)p; p += (size_t)Nn * HEADS * 4;
    float* a_src2 = (float*)p; p += (size_t)Nn * 4;
    float* a_dst2 = (float*)p; p += (size_t)Nn * 4;
    int* deg     = (int*)p; p += (size_t)Nn * 4;
    int* rowptr  = (int*)p; p += (size_t)(Nn + 1) * 4;
    int* cursor  = (int*)p; p += (size_t)Nn * 4;
    int* bsum    = (int*)p; p += 256 * 4;
    int* boff    = (int*)p; p += 256 * 4;
    int* csr_src = (int*)p; p += (size_t)E * 4;

    // --- setup: weight casts + deg zero ---
    {
        const int total = F1 * F1 + F1 * F2 + Nn;
        setup_kernel<<<(total + 255) / 256, 256, 0, stream>>>(
            W1, W2, W1T, W2T, deg, Nn);
    }

    // --- CSR build (by dst) ---
    hist_kernel<<<(E + 255) / 256, 256, 0, stream>>>(ei, E, deg);
    scan_bsum<<<NB, 256, 0, stream>>>(deg, bsum, Nn);
    scan_boff<<<1, 256, 0, stream>>>(bsum, boff, rowptr, NB, Nn);
    scan_write<<<NB, 256, 0, stream>>>(deg, boff, rowptr, cursor, Nn);
    scatter_kernel<<<(E + 255) / 256, 256, 0, stream>>>(ei, E, cursor, csr_src);

    // --- layer 1 ---
    {
        dim3 grid((Nn + 127) / 128, F1 / 128);
        mfma_gemm<128, true, true><<<grid, 256, 0, stream>>>(
            x, W1T, h1b, Nn, F1, F1);
    }
    att1_kernel<<<(Nn * HEADS + 255) / 256, 256, 0, stream>>>(
        h1b, att_src1, att_dst1, a_src1, a_dst1, Nn);
    gather1_kernel<<<(Nn + 3) / 4, 256, 0, stream>>>(
        rowptr, csr_src, a_src1, a_dst1, h1b, b1, out1b, Nn);

    // --- layer 2 ---
    {
        dim3 grid((Nn + 127) / 128, F2 / 64);
        mfma_gemm<64, false, true><<<grid, 256, 0, stream>>>(
            out1b, W2T, h2b, Nn, F2, F1);
    }
    att2_kernel<<<(Nn + 255) / 256, 256, 0, stream>>>(
        h2b, att_src2, att_dst2, a_src2, a_dst2, Nn);
    gather2_kernel<<<(Nn + 3) / 4, 256, 0, stream>>>(
        rowptr, csr_src, a_src2, a_dst2, h2b, b2, out, Nn);
}

// Round 7
// 336.228 us; speedup vs baseline: 10.1507x; 1.0456x over previous
//
#include <hip/hip_runtime.h>
#include <hip/hip_bf16.h>

// GAT 2-layer forward. N=50000, E=800000 (+N self loops), IN=256,
// layer1: 8 heads x 32 (concat -> 256), relu, layer2: 256 -> 64, 1 head.
// Round 7: multi-edge-per-wave gathers. gather1: 32 lanes x 16B per edge
// (2 edges/wave-instr); gather2: 16 lanes x 8B per edge (4 edges/wave-instr).
// Halves/quarters instruction issue per edge at identical traffic.

#define HEADS 8
#define HID 32
#define F1 256   // IN and layer-1 output width (8*32)
#define F2 64    // layer-2 output width
#define NEG_SLOPE 0.2f
#define SCAN_CHUNK 1024   // nodes per scan block (256 thr x 4)

typedef __attribute__((ext_vector_type(8))) short bf16x8;
typedef __attribute__((ext_vector_type(4))) float f32x4;
typedef __attribute__((ext_vector_type(8))) unsigned short u16x8;

__device__ __forceinline__ unsigned short f2b(float f) {
    union { float f; unsigned int i; } x; x.f = f;
    unsigned int r = x.i + 0x7fffu + ((x.i >> 16) & 1u);  // RNE
    return (unsigned short)(r >> 16);
}
__device__ __forceinline__ float b2f(unsigned short u) {
    union { unsigned int i; float f; } x; x.i = ((unsigned int)u) << 16;
    return x.f;
}
__device__ __forceinline__ float leaky(float v) {
    return v > 0.f ? v : NEG_SLOPE * v;
}

// ---------------- setup: W1T, W2T casts + deg zero (merged) -------------
__global__ void setup_kernel(const float* __restrict__ W1,
                             const float* __restrict__ W2,
                             unsigned short* __restrict__ W1T,
                             unsigned short* __restrict__ W2T,
                             int* __restrict__ deg, int Nn) {
    const int i = blockIdx.x * 256 + threadIdx.x;
    if (i < F1 * F1) {                       // W1 [F1,F1] -> W1T [n][k]
        const int k = i >> 8, n = i & (F1 - 1);
        W1T[(size_t)n * F1 + k] = f2b(W1[i]);
    } else if (i < F1 * F1 + F1 * F2) {      // W2 [F1,F2] -> W2T [n][k]
        const int j = i - F1 * F1;
        const int k = j >> 6, n = j & (F2 - 1);
        W2T[(size_t)n * F1 + k] = f2b(W2[j]);
    } else if (i < F1 * F1 + F1 * F2 + Nn) {
        deg[i - F1 * F1 - F1 * F2] = 0;
    }
}

// ---------------- MFMA GEMM: C[M,N] = A[M,K] @ BT[N,K]^T ----------------
// A bf16 or fp32 (cast fused in staging); BT bf16; C bf16 or fp32.
template<int BN, bool A_FP32, bool OUT_BF16>
__global__ __launch_bounds__(256) void mfma_gemm(
        const void* __restrict__ A,
        const unsigned short* __restrict__ BT,
        void* __restrict__ C, int M, int N, int K) {
    constexpr int BM = 128, BK = 32;
    __shared__ unsigned short As[BM * BK];
    __shared__ unsigned short Bs[BN * BK];
    const int tid = threadIdx.x;
    const int wave = tid >> 6, lane = tid & 63;
    const int quad = lane >> 4, l16 = lane & 15;
    const int brow = blockIdx.x * BM;
    const int bcol = blockIdx.y * BN;

    constexpr int MI = (BN == 128) ? 4 : 2;
    constexpr int NJ = 4;
    const int wm = (BN == 128) ? (wave & 1) * 64 : wave * 32;
    const int wn = (BN == 128) ? (wave >> 1) * 64 : 0;

    f32x4 acc[MI][NJ] = {};

    for (int k0 = 0; k0 < K; k0 += BK) {
#pragma unroll
        for (int it = 0; it < (BM * BK) / (256 * 8); ++it) {
            const int idx = it * 256 + tid;
            const int r = idx >> 2;
            const int kk = (idx & 3) * 8;
            const int gr = brow + r;
            if (A_FP32) {
                const float* Af = (const float*)A;
                float4 a0 = make_float4(0.f, 0.f, 0.f, 0.f);
                float4 a1 = make_float4(0.f, 0.f, 0.f, 0.f);
                if (gr < M) {
                    a0 = *(const float4*)&Af[(size_t)gr * K + k0 + kk];
                    a1 = *(const float4*)&Af[(size_t)gr * K + k0 + kk + 4];
                }
                ushort4 lo, hi;
                lo.x = f2b(a0.x); lo.y = f2b(a0.y); lo.z = f2b(a0.z); lo.w = f2b(a0.w);
                hi.x = f2b(a1.x); hi.y = f2b(a1.y); hi.z = f2b(a1.z); hi.w = f2b(a1.w);
                *(ushort4*)&As[r * BK + kk] = lo;
                *(ushort4*)&As[r * BK + kk + 4] = hi;
            } else {
                const unsigned short* Ab = (const unsigned short*)A;
                uint4 v = make_uint4(0u, 0u, 0u, 0u);
                if (gr < M) v = *(const uint4*)&Ab[(size_t)gr * K + k0 + kk];
                *(uint4*)&As[r * BK + kk] = v;
            }
        }
#pragma unroll
        for (int it = 0; it < (BN * BK) / (256 * 8); ++it) {
            const int idx = it * 256 + tid;
            const int r = idx >> 2;
            const int kk = (idx & 3) * 8;
            const uint4 v = *(const uint4*)&BT[(size_t)(bcol + r) * K + k0 + kk];
            *(uint4*)&Bs[r * BK + kk] = v;
        }
        __syncthreads();
        bf16x8 af[MI], bfr[NJ];
#pragma unroll
        for (int i = 0; i < MI; ++i)
            af[i] = *(const bf16x8*)&As[(wm + i * 16 + l16) * BK + quad * 8];
#pragma unroll
        for (int j = 0; j < NJ; ++j)
            bfr[j] = *(const bf16x8*)&Bs[(wn + j * 16 + l16) * BK + quad * 8];
#pragma unroll
        for (int i = 0; i < MI; ++i)
#pragma unroll
            for (int j = 0; j < NJ; ++j)
                acc[i][j] = __builtin_amdgcn_mfma_f32_16x16x32_bf16(
                    af[i], bfr[j], acc[i][j], 0, 0, 0);
        __syncthreads();
    }
#pragma unroll
    for (int i = 0; i < MI; ++i) {
#pragma unroll
        for (int r = 0; r < 4; ++r) {
            const int row = brow + wm + i * 16 + quad * 4 + r;
            if (row >= M) continue;
#pragma unroll
            for (int j = 0; j < NJ; ++j) {
                const int col = bcol + wn + j * 16 + l16;
                const float v = acc[i][j][r];
                if (OUT_BF16)
                    ((unsigned short*)C)[(size_t)row * N + col] = f2b(v);
                else
                    ((float*)C)[(size_t)row * N + col] = v;
            }
        }
    }
}

// ---------------- attention coefficients ----------------
__global__ void att1_kernel(const unsigned short* __restrict__ h1b,
                            const float* __restrict__ att_src,
                            const float* __restrict__ att_dst,
                            float* __restrict__ a_src,
                            float* __restrict__ a_dst, int Nn) {
    const int i = blockIdx.x * blockDim.x + threadIdx.x;
    if (i >= Nn * HEADS) return;
    const int n = i >> 3, h = i & 7;
    const unsigned short* hp = h1b + (size_t)n * F1 + h * HID;
    const float* as = att_src + h * HID;
    const float* ad = att_dst + h * HID;
    float s = 0.f, d = 0.f;
#pragma unroll
    for (int f = 0; f < HID; ++f) {
        const float v = b2f(hp[f]);
        s += v * as[f];
        d += v * ad[f];
    }
    a_src[i] = s;
    a_dst[i] = d;
}

__global__ void att2_kernel(const unsigned short* __restrict__ h2b,
                            const float* __restrict__ att_src,
                            const float* __restrict__ att_dst,
                            float* __restrict__ a_src,
                            float* __restrict__ a_dst, int Nn) {
    const int n = blockIdx.x * blockDim.x + threadIdx.x;
    if (n >= Nn) return;
    const unsigned short* hp = h2b + (size_t)n * F2;
    float s = 0.f, d = 0.f;
#pragma unroll
    for (int f = 0; f < F2; ++f) {
        const float v = b2f(hp[f]);
        s += v * att_src[f];
        d += v * att_dst[f];
    }
    a_src[n] = s;
    a_dst[n] = d;
}

// ---------------- CSR build ----------------
__global__ void hist_kernel(const int* __restrict__ ei, int E,
                            int* __restrict__ deg) {
    const int e = blockIdx.x * blockDim.x + threadIdx.x;
    if (e < E) atomicAdd(&deg[ei[E + e]], 1);
}

__global__ __launch_bounds__(256) void scan_bsum(const int* __restrict__ deg,
                                                 int* __restrict__ bsum, int Nn) {
    const int base = blockIdx.x * SCAN_CHUNK + threadIdx.x * 4;
    int s = 0;
#pragma unroll
    for (int j = 0; j < 4; ++j) {
        const int i = base + j;
        if (i < Nn) s += deg[i];
    }
#pragma unroll
    for (int off = 32; off > 0; off >>= 1) s += __shfl_down(s, off, 64);
    __shared__ int ws[4];
    if ((threadIdx.x & 63) == 0) ws[threadIdx.x >> 6] = s;
    __syncthreads();
    if (threadIdx.x == 0) bsum[blockIdx.x] = ws[0] + ws[1] + ws[2] + ws[3];
}

__global__ __launch_bounds__(256) void scan_boff(const int* __restrict__ bsum,
                                                 int* __restrict__ boff,
                                                 int* __restrict__ rowptr,
                                                 int B, int Nn) {
    __shared__ int sums[256];
    const int tid = threadIdx.x;
    const int v = (tid < B) ? bsum[tid] : 0;
    sums[tid] = v;
    __syncthreads();
    for (int off = 1; off < 256; off <<= 1) {
        const int cur = sums[tid];
        const int add = (tid >= off) ? sums[tid - off] : 0;
        __syncthreads();
        sums[tid] = cur + add;
        __syncthreads();
    }
    if (tid < B) boff[tid] = sums[tid] - v;   // exclusive
    if (tid == 255) rowptr[Nn] = sums[255];   // total
}

__global__ __launch_bounds__(256) void scan_write(const int* __restrict__ deg,
                                                  const int* __restrict__ boff,
                                                  int* __restrict__ rowptr,
                                                  int* __restrict__ cursor, int Nn) {
    const int tid = threadIdx.x;
    const int base = blockIdx.x * SCAN_CHUNK + tid * 4;
    int v[4];
    int s = 0;
#pragma unroll
    for (int j = 0; j < 4; ++j) {
        const int i = base + j;
        v[j] = (i < Nn) ? deg[i] : 0;
        s += v[j];
    }
    __shared__ int sums[256];
    sums[tid] = s;
    __syncthreads();
    for (int off = 1; off < 256; off <<= 1) {
        const int cur = sums[tid];
        const int add = (tid >= off) ? sums[tid - off] : 0;
        __syncthreads();
        sums[tid] = cur + add;
        __syncthreads();
    }
    int off = boff[blockIdx.x] + sums[tid] - s;  // exclusive prefix
#pragma unroll
    for (int j = 0; j < 4; ++j) {
        const int i = base + j;
        if (i < Nn) {
            rowptr[i] = off;
            cursor[i] = off;
            off += v[j];
        }
    }
}

__global__ void scatter_kernel(const int* __restrict__ ei, int E,
                               int* __restrict__ cursor,
                               int* __restrict__ csr_src) {
    const int e = blockIdx.x * blockDim.x + threadIdx.x;
    if (e >= E) return;
    const int d = ei[E + e];
    const int pos = atomicAdd(&cursor[d], 1);
    csr_src[pos] = ei[e];
}

// ---------------- layer-1 gather: 32 lanes x 16B per edge ----------------
// Wave covers 2 nodes (lanes 0-31 / 32-63). Lane l of its group handles
// channels c = 8l..8l+7 (one uint4 / dwordx4 per edge); head h = l>>2.
__global__ __launch_bounds__(256) void gather1_kernel(
        const int* __restrict__ rowptr, const int* __restrict__ csr_src,
        const float* __restrict__ a_src, const float* __restrict__ a_dst,
        const unsigned short* __restrict__ h1b, const float* __restrict__ b1,
        unsigned short* __restrict__ out1b, int Nn) {
    const int lane = threadIdx.x & 63;
    const int sub  = lane >> 5;          // which of 2 nodes in the wave
    const int l    = lane & 31;
    int d = blockIdx.x * 8 + (threadIdx.x >> 6) * 2 + sub;
    const bool valid = d < Nn;
    if (!valid) d = Nn - 1;
    const int h = l >> 2;                // head (4 lanes per head)
    const int c = l * 8;                 // 8 channels per lane

    const float adst = a_dst[d * HEADS + h];
    float acc[8];
    float denom;
    {   // self-loop
        const float w = __expf(leaky(a_src[d * HEADS + h] + adst));
        const u16x8 v = *(const u16x8*)&h1b[(size_t)d * F1 + c];
        denom = w;
#pragma unroll
        for (int q = 0; q < 8; ++q) acc[q] = w * b2f(v[q]);
    }
    const int beg = rowptr[d], end = rowptr[d + 1];
    int i = beg;
    for (; i + 4 <= end; i += 4) {
        int s[4];
        float e[4];
        u16x8 vv[4];
#pragma unroll
        for (int j = 0; j < 4; ++j) s[j] = csr_src[i + j];
#pragma unroll
        for (int j = 0; j < 4; ++j) e[j] = a_src[s[j] * HEADS + h];
#pragma unroll
        for (int j = 0; j < 4; ++j)
            vv[j] = *(const u16x8*)&h1b[(size_t)s[j] * F1 + c];
#pragma unroll
        for (int j = 0; j < 4; ++j) {
            const float w = __expf(leaky(e[j] + adst));
            denom += w;
#pragma unroll
            for (int q = 0; q < 8; ++q) acc[q] += w * b2f(vv[j][q]);
        }
    }
    for (; i < end; ++i) {
        const int s = csr_src[i];
        const float w = __expf(leaky(a_src[s * HEADS + h] + adst));
        const u16x8 v = *(const u16x8*)&h1b[(size_t)s * F1 + c];
        denom += w;
#pragma unroll
        for (int q = 0; q < 8; ++q) acc[q] += w * b2f(v[q]);
    }
    if (valid) {
        const float inv = 1.f / denom;
        u16x8 o;
#pragma unroll
        for (int q = 0; q < 8; ++q)
            o[q] = f2b(fmaxf(acc[q] * inv + b1[c + q], 0.f));
        *(u16x8*)&out1b[(size_t)d * F1 + c] = o;
    }
}

// ---------------- layer-2 gather: 16 lanes x 8B per edge ----------------
// Wave covers 4 nodes. Lane l of its group handles channels c = 4l..4l+3.
__global__ __launch_bounds__(256) void gather2_kernel(
        const int* __restrict__ rowptr, const int* __restrict__ csr_src,
        const float* __restrict__ a_src, const float* __restrict__ a_dst,
        const unsigned short* __restrict__ h2b, const float* __restrict__ b2,
        float* __restrict__ out, int Nn) {
    const int lane = threadIdx.x & 63;
    const int sub  = lane >> 4;          // which of 4 nodes in the wave
    const int l    = lane & 15;
    int d = blockIdx.x * 16 + (threadIdx.x >> 6) * 4 + sub;
    const bool valid = d < Nn;
    if (!valid) d = Nn - 1;
    const int c = l * 4;

    const float adst = a_dst[d];
    float a0, a1, a2, a3, denom;
    {   // self-loop
        const float w = __expf(leaky(a_src[d] + adst));
        const ushort4 v = *(const ushort4*)&h2b[(size_t)d * F2 + c];
        denom = w;
        a0 = w * b2f(v.x); a1 = w * b2f(v.y);
        a2 = w * b2f(v.z); a3 = w * b2f(v.w);
    }
    const int beg = rowptr[d], end = rowptr[d + 1];
    int i = beg;
    for (; i + 4 <= end; i += 4) {
        int s[4];
        float e[4];
        ushort4 vv[4];
#pragma unroll
        for (int j = 0; j < 4; ++j) s[j] = csr_src[i + j];
#pragma unroll
        for (int j = 0; j < 4; ++j) e[j] = a_src[s[j]];
#pragma unroll
        for (int j = 0; j < 4; ++j)
            vv[j] = *(const ushort4*)&h2b[(size_t)s[j] * F2 + c];
#pragma unroll
        for (int j = 0; j < 4; ++j) {
            const float w = __expf(leaky(e[j] + adst));
            denom += w;
            a0 += w * b2f(vv[j].x); a1 += w * b2f(vv[j].y);
            a2 += w * b2f(vv[j].z); a3 += w * b2f(vv[j].w);
        }
    }
    for (; i < end; ++i) {
        const int s = csr_src[i];
        const float w = __expf(leaky(a_src[s] + adst));
        const ushort4 v = *(const ushort4*)&h2b[(size_t)s * F2 + c];
        denom += w;
        a0 += w * b2f(v.x); a1 += w * b2f(v.y);
        a2 += w * b2f(v.z); a3 += w * b2f(v.w);
    }
    if (valid) {
        const float inv = 1.f / denom;
        float4 o;
        o.x = a0 * inv + b2[c + 0];
        o.y = a1 * inv + b2[c + 1];
        o.z = a2 * inv + b2[c + 2];
        o.w = a3 * inv + b2[c + 3];
        *(float4*)&out[(size_t)d * F2 + c] = o;
    }
}

extern "C" void kernel_launch(void* const* d_in, const int* in_sizes, int n_in,
                              void* d_out, int out_size, void* d_ws, size_t ws_size,
                              hipStream_t stream) {
    const float* x        = (const float*)d_in[0];
    const int*   ei       = (const int*)d_in[1];     // [2, E]
    const float* W1       = (const float*)d_in[2];   // [256,256]
    const float* att_src1 = (const float*)d_in[3];   // [8,32]
    const float* att_dst1 = (const float*)d_in[4];
    const float* b1       = (const float*)d_in[5];   // [256]
    const float* W2       = (const float*)d_in[6];   // [256,64]
    const float* att_src2 = (const float*)d_in[7];   // [1,64]
    const float* att_dst2 = (const float*)d_in[8];
    const float* b2       = (const float*)d_in[9];   // [64]
    float* out = (float*)d_out;                      // [N,64]

    const int Nn = in_sizes[0] / F1;    // 50000
    const int E  = in_sizes[1] / 2;     // 800000
    const int NB = (Nn + SCAN_CHUNK - 1) / SCAN_CHUNK;  // scan blocks (<=256)

    // workspace layout — wide-aligned arrays first
    char* p = (char*)d_ws;
    unsigned short* h1b   = (unsigned short*)p; p += (size_t)Nn * F1 * 2;
    unsigned short* out1b = (unsigned short*)p; p += (size_t)Nn * F1 * 2;
    unsigned short* W1T   = (unsigned short*)p; p += (size_t)F1 * F1 * 2;
    unsigned short* W2T   = (unsigned short*)p; p += (size_t)F2 * F1 * 2;
    unsigned short* h2b   = (unsigned short*)p; p += (size_t)Nn * F2 * 2;
    float* a_src1 = (float*)p; p += (size_t)Nn * HEADS * 4;
    float* a_dst1 = (float*)p; p += (size_t)Nn * HEADS * 4;
    float* a_src2 = (float*)p; p += (size_t)Nn * 4;
    float* a_dst2 = (float*)p; p += (size_t)Nn * 4;
    int* deg     = (int*)p; p += (size_t)Nn * 4;
    int* rowptr  = (int*)p; p += (size_t)(Nn + 1) * 4;
    int* cursor  = (int*)p; p += (size_t)Nn * 4;
    int* bsum    = (int*)p; p += 256 * 4;
    int* boff    = (int*)p; p += 256 * 4;
    int* csr_src = (int*)p; p += (size_t)E * 4;

    // --- setup: weight casts + deg zero ---
    {
        const int total = F1 * F1 + F1 * F2 + Nn;
        setup_kernel<<<(total + 255) / 256, 256, 0, stream>>>(
            W1, W2, W1T, W2T, deg, Nn);
    }

    // --- CSR build (by dst) ---
    hist_kernel<<<(E + 255) / 256, 256, 0, stream>>>(ei, E, deg);
    scan_bsum<<<NB, 256, 0, stream>>>(deg, bsum, Nn);
    scan_boff<<<1, 256, 0, stream>>>(bsum, boff, rowptr, NB, Nn);
    scan_write<<<NB, 256, 0, stream>>>(deg, boff, rowptr, cursor, Nn);
    scatter_kernel<<<(E + 255) / 256, 256, 0, stream>>>(ei, E, cursor, csr_src);

    // --- layer 1 ---
    {
        dim3 grid((Nn + 127) / 128, F1 / 128);
        mfma_gemm<128, true, true><<<grid, 256, 0, stream>>>(
            x, W1T, h1b, Nn, F1, F1);
    }
    att1_kernel<<<(Nn * HEADS + 255) / 256, 256, 0, stream>>>(
        h1b, att_src1, att_dst1, a_src1, a_dst1, Nn);
    gather1_kernel<<<(Nn + 7) / 8, 256, 0, stream>>>(
        rowptr, csr_src, a_src1, a_dst1, h1b, b1, out1b, Nn);

    // --- layer 2 ---
    {
        dim3 grid((Nn + 127) / 128, F2 / 64);
        mfma_gemm<64, false, true><<<grid, 256, 0, stream>>>(
            out1b, W2T, h2b, Nn, F2, F1);
    }
    att2_kernel<<<(Nn + 255) / 256, 256, 0, stream>>>(
        h2b, att_src2, att_dst2, a_src2, a_dst2, Nn);
    gather2_kernel<<<(Nn + 15) / 16, 256, 0, stream>>>(
        rowptr, csr_src, a_src2, a_dst2, h2b, b2, out, Nn);
}